// Round 2
// baseline (8233.781 us; speedup 1.0000x reference)
//
#include <hip/hip_runtime.h>
#include <hip/hip_bf16.h>
#include <math.h>

#define DIM 256

__device__ inline float b2f(unsigned short u) {
    union { unsigned int i; float f; } c; c.i = ((unsigned int)u) << 16; return c.f;
}
__device__ inline unsigned short f2b(float f) {
    __hip_bfloat16 h = __float2bfloat16(f);
    return *reinterpret_cast<unsigned short*>(&h);
}

// ---------------- scatter-add (mean numerator + counts), fp32 atomics ----------------
// One 64-lane group per edge; each lane handles 4 consecutive floats.
template<bool SRCBF16, bool RANGED>
__global__ __launch_bounds__(256) void k_scatter(
    const void* __restrict__ srcp, const int* __restrict__ sidx,
    const int* __restrict__ didx, int dbase, int dcnt,
    float* __restrict__ agg, float* __restrict__ cnt, int nedges)
{
    int gid  = (blockIdx.x * 256 + threadIdx.x) >> 6;
    int lane = threadIdx.x & 63;
    if (gid >= nedges) return;
    int d = didx[gid];
    if (RANGED) { if (d < dbase || d >= dbase + dcnt) return; }
    int s = sidx[gid];
    float4 v;
    if (SRCBF16) {
        const unsigned short* src = (const unsigned short*)srcp;
        ushort4 u = *(const ushort4*)(src + (size_t)s * DIM + lane * 4);
        v = make_float4(b2f(u.x), b2f(u.y), b2f(u.z), b2f(u.w));
    } else {
        v = *(const float4*)((const float*)srcp + (size_t)s * DIM + lane * 4);
    }
    int dl = RANGED ? (d - dbase) : d;
    float* dst = agg + (size_t)dl * DIM + lane * 4;
    atomicAdd(dst + 0, v.x);
    atomicAdd(dst + 1, v.y);
    atomicAdd(dst + 2, v.z);
    atomicAdd(dst + 3, v.w);
    if (lane == 0) atomicAdd(cnt + d, 1.0f);
}

// ---------------- tiled GEMM: C = act(scale(A) @ W^T + b) ----------------
// A: [M,256] (fp32 or bf16), W: [256,256] fp32 row-major. 64x64 tile, BK=16,
// 256 threads, 4x4 micro-tile per thread. Output fp32 or bf16.
template<bool INBF16, bool OUTBF16, bool SCALE, bool RELU>
__global__ __launch_bounds__(256) void k_gemm(
    const void* __restrict__ Ap, const float* __restrict__ W,
    const float* __restrict__ bias, const float* __restrict__ cnt,
    void* __restrict__ Cp, int M)
{
    __shared__ float As[16][68];   // [k][m], stride 68 breaks bank conflicts
    __shared__ float Ws[16][68];   // [k][n]
    const int tid  = threadIdx.x;
    const int m0   = blockIdx.x * 64;
    const int n0   = blockIdx.y * 64;
    const int lrow = tid >> 2;          // 0..63
    const int lk   = (tid & 3) * 4;     // 0,4,8,12
    const int arow = m0 + lrow;
    const int wrow = n0 + lrow;
    float scale = 1.0f;
    if (SCALE && arow < M) scale = 1.0f / fmaxf(cnt[arow], 1.0f);
    const int tm = (tid & 15) * 4;
    const int tn = (tid >> 4) * 4;
    float acc[4][4] = {};
    for (int k0 = 0; k0 < DIM; k0 += 16) {
        float4 av = make_float4(0.f, 0.f, 0.f, 0.f);
        if (arow < M) {
            if (INBF16) {
                const unsigned short* A = (const unsigned short*)Ap;
                ushort4 u = *(const ushort4*)(A + (size_t)arow * DIM + k0 + lk);
                av = make_float4(b2f(u.x), b2f(u.y), b2f(u.z), b2f(u.w));
            } else {
                av = *(const float4*)((const float*)Ap + (size_t)arow * DIM + k0 + lk);
            }
        }
        if (SCALE) { av.x *= scale; av.y *= scale; av.z *= scale; av.w *= scale; }
        const float4 wv = *(const float4*)(W + (size_t)wrow * DIM + k0 + lk);
        __syncthreads();
        As[lk + 0][lrow] = av.x; As[lk + 1][lrow] = av.y;
        As[lk + 2][lrow] = av.z; As[lk + 3][lrow] = av.w;
        Ws[lk + 0][lrow] = wv.x; Ws[lk + 1][lrow] = wv.y;
        Ws[lk + 2][lrow] = wv.z; Ws[lk + 3][lrow] = wv.w;
        __syncthreads();
        #pragma unroll
        for (int k = 0; k < 16; ++k) {
            const float4 a = *(const float4*)&As[k][tm];
            const float4 w = *(const float4*)&Ws[k][tn];
            acc[0][0] += a.x * w.x; acc[0][1] += a.x * w.y; acc[0][2] += a.x * w.z; acc[0][3] += a.x * w.w;
            acc[1][0] += a.y * w.x; acc[1][1] += a.y * w.y; acc[1][2] += a.y * w.z; acc[1][3] += a.y * w.w;
            acc[2][0] += a.z * w.x; acc[2][1] += a.z * w.y; acc[2][2] += a.z * w.z; acc[2][3] += a.z * w.w;
            acc[3][0] += a.w * w.x; acc[3][1] += a.w * w.y; acc[3][2] += a.w * w.z; acc[3][3] += a.w * w.w;
        }
    }
    const float4 bv = *(const float4*)(bias + n0 + tn);
    #pragma unroll
    for (int i = 0; i < 4; ++i) {
        int row = m0 + tm + i;
        if (row >= M) break;
        float4 o;
        o.x = acc[i][0] + bv.x;
        o.y = acc[i][1] + bv.y;
        o.z = acc[i][2] + bv.z;
        o.w = acc[i][3] + bv.w;
        if (RELU) {
            o.x = fmaxf(o.x, 0.f); o.y = fmaxf(o.y, 0.f);
            o.z = fmaxf(o.z, 0.f); o.w = fmaxf(o.w, 0.f);
        }
        if (OUTBF16) {
            unsigned short* C = (unsigned short*)Cp;
            ushort4 o4; o4.x = f2b(o.x); o4.y = f2b(o.y); o4.z = f2b(o.z); o4.w = f2b(o.w);
            *(ushort4*)(C + (size_t)row * DIM + n0 + tn) = o4;
        } else {
            *(float4*)((float*)Cp + (size_t)row * DIM + n0 + tn) = o;
        }
    }
}

// ---------------- finalize (in place): V = w0*E + w1*(vagg/max(vcnt,1)) ----------------
__global__ __launch_bounds__(256) void k_finalize(
    const float* __restrict__ E, const float* __restrict__ vagg,
    const float* __restrict__ vcnt, const float* __restrict__ alpha,
    float* __restrict__ V, int NE)
{
    float a0 = alpha[0], a1 = alpha[1];
    float mx = fmaxf(a0, a1);
    float e0 = expf(a0 - mx), e1 = expf(a1 - mx);
    float w0 = e0 / (e0 + e1), w1 = e1 / (e0 + e1);
    size_t total = (size_t)NE * (DIM / 4);
    for (size_t i = (size_t)blockIdx.x * blockDim.x + threadIdx.x; i < total;
         i += (size_t)gridDim.x * blockDim.x) {
        int row = (int)(i >> 6);
        float s = w1 / fmaxf(vcnt[row], 1.0f);
        float4 e = ((const float4*)E)[i];
        float4 v = ((const float4*)vagg)[i];
        float4 o;
        o.x = w0 * e.x + s * v.x;
        o.y = w0 * e.y + s * v.y;
        o.z = w0 * e.z + s * v.z;
        o.w = w0 * e.w + s * v.w;
        ((float4*)V)[i] = o;
    }
}

// ---------------- TransE score: out = gamma - ||V[h]+R[r]-V[t]|| ----------------
__global__ __launch_bounds__(256) void k_score(
    const float* __restrict__ V, const float* __restrict__ R,
    const int* __restrict__ triples, const float* __restrict__ gamma,
    float* __restrict__ out, int B)
{
    int t    = (blockIdx.x * 256 + threadIdx.x) >> 6;
    int lane = threadIdx.x & 63;
    if (t >= B) return;
    int h  = triples[t * 3 + 0];
    int r  = triples[t * 3 + 1];
    int tl = triples[t * 3 + 2];
    float4 vh = *(const float4*)(V + (size_t)h  * DIM + lane * 4);
    float4 vr = *(const float4*)(R + (size_t)r  * DIM + lane * 4);
    float4 vt = *(const float4*)(V + (size_t)tl * DIM + lane * 4);
    float dx = vh.x + vr.x - vt.x;
    float dy = vh.y + vr.y - vt.y;
    float dz = vh.z + vr.z - vt.z;
    float dw = vh.w + vr.w - vt.w;
    float s = dx * dx + dy * dy + dz * dz + dw * dw;
    #pragma unroll
    for (int off = 32; off > 0; off >>= 1) s += __shfl_xor(s, off);
    if (lane == 0) out[t] = gamma[0] - sqrtf(s);
}

extern "C" void kernel_launch(void* const* d_in, const int* in_sizes, int n_in,
                              void* d_out, int out_size, void* d_ws, size_t ws_size,
                              hipStream_t stream)
{
    const float* E      = (const float*)d_in[0];
    const float* R      = (const float*)d_in[1];
    const float* lin2_w = (const float*)d_in[2];
    const float* lin2_b = (const float*)d_in[3];
    const float* lin3_w = (const float*)d_in[4];
    const float* lin3_b = (const float*)d_in[5];
    const float* t2e_w  = (const float*)d_in[6];
    const float* t2e_b  = (const float*)d_in[7];
    const float* alpha  = (const float*)d_in[8];
    const float* gamma  = (const float*)d_in[9];
    const int*   et     = (const int*)d_in[10];
    const int*   tt     = (const int*)d_in[11];
    const int*   etet   = (const int*)d_in[12];
    const int*   trip   = (const int*)d_in[13];

    const int NE   = in_sizes[0] / DIM;          // 100000
    const int ET   = in_sizes[10] / 2;           // 900000
    const int TT   = in_sizes[11] / 2;           // 600000
    const int ETET = in_sizes[12] / 2;           // 600000
    const int B    = in_sizes[13] / 3;           // 8192
    const int NT   = 300000, NTET = 150000, CHUNK = 150000;

    // ---- workspace layout: A (153.6 MB fp32) | B (153.6 MB bf16) | counts ----
    char* ws = (char*)d_ws;
    const size_t SZA = (size_t)CHUNK * DIM * sizeof(float);         // 153,600,000 B
    float*          A   = (float*)ws;
    unsigned short* Bh  = (unsigned short*)(ws + SZA);              // 300000x256 bf16
    float* cntTri = (float*)(ws + 2 * SZA);
    float* cntTet = cntTri + NT;
    float* cntEnt = cntTet + NTET;
    const size_t REQ = 2 * SZA + (size_t)(NT + NTET + NE) * sizeof(float);
    if (ws_size < REQ) return;   // signals as absmax failure, not a core dump

    hipMemsetAsync(cntTri, 0, (size_t)(NT + NTET + NE) * sizeof(float), stream);

    // ---- stage 1: entity -> triangle mean + lin2 + relu, 2 dst-chunks ----
    dim3 gG((CHUNK + 63) / 64, 4);
    for (int c = 0; c < 2; ++c) {
        hipMemsetAsync(A, 0, SZA, stream);
        k_scatter<false, true><<<(ET + 3) / 4, 256, 0, stream>>>(
            E, et, et + ET, c * CHUNK, CHUNK, A, cntTri, ET);
        k_gemm<false, true, true, true><<<gG, 256, 0, stream>>>(
            A, lin2_w, lin2_b, cntTri + c * CHUNK,
            Bh + (size_t)c * CHUNK * DIM, CHUNK);
    }

    // ---- stage 2: triangle -> tetra mean + lin3 + relu ----
    hipMemsetAsync(A, 0, SZA, stream);
    k_scatter<true, false><<<(TT + 3) / 4, 256, 0, stream>>>(
        Bh, tt, tt + TT, 0, 0, A, cntTet, TT);
    k_gemm<false, true, true, true><<<gG, 256, 0, stream>>>(
        A, lin3_w, lin3_b, cntTet, Bh, NTET);              // tet_emb -> B[0:76.8MB]

    // ---- stage 3: t2e projection (bf16 in -> bf16 out, disjoint B halves) ----
    k_gemm<true, true, false, false><<<gG, 256, 0, stream>>>(
        Bh, t2e_w, t2e_b, nullptr, Bh + (size_t)NTET * DIM, NTET);

    // ---- stage 4: tetra -> entity mean, fuse with E ----
    hipMemsetAsync(A, 0, (size_t)NE * DIM * sizeof(float), stream);
    k_scatter<true, false><<<(ETET + 3) / 4, 256, 0, stream>>>(
        Bh + (size_t)NTET * DIM, etet + ETET, etet, 0, 0, A, cntEnt, ETET);
    k_finalize<<<2048, 256, 0, stream>>>(E, A, cntEnt, alpha, A, NE);

    // ---- stage 5: TransE scores ----
    k_score<<<(B + 3) / 4, 256, 0, stream>>>(A, R, trip, gamma, (float*)d_out, B);
}

// Round 3
// 1267.478 us; speedup vs baseline: 6.4962x; 6.4962x over previous
//
#include <hip/hip_runtime.h>
#include <hip/hip_bf16.h>
#include <math.h>

#define DIM 256
#define SBS 256
#define SIT 8            // scan items per thread -> 2048 per block

__device__ inline float b2f(unsigned short u) {
    union { unsigned int i; float f; } c; c.i = ((unsigned int)u) << 16; return c.f;
}
__device__ inline unsigned short f2b(float f) {
    __hip_bfloat16 h = __float2bfloat16(f);
    return *reinterpret_cast<unsigned short*>(&h);
}

// ================= sort-by-destination machinery =================
__global__ __launch_bounds__(256) void k_count(
    const int* __restrict__ didx, int* __restrict__ cnt, int ne)
{
    int e = blockIdx.x * 256 + threadIdx.x;
    if (e < ne) atomicAdd(&cnt[didx[e]], 1);
}

__global__ __launch_bounds__(SBS) void k_scan_block(
    const int* __restrict__ cnt, int* __restrict__ rowOff,
    int* __restrict__ blockSums, int n)
{
    __shared__ int lds[SBS];
    const int t = threadIdx.x;
    const int tbase = blockIdx.x * SBS * SIT + t * SIT;
    int v[SIT]; int tsum = 0;
    #pragma unroll
    for (int i = 0; i < SIT; ++i) {
        int idx = tbase + i;
        v[i] = (idx < n) ? cnt[idx] : 0;
        tsum += v[i];
    }
    lds[t] = tsum;
    __syncthreads();
    #pragma unroll
    for (int off = 1; off < SBS; off <<= 1) {
        int y = (t >= off) ? lds[t - off] : 0;
        __syncthreads();
        lds[t] += y;
        __syncthreads();
    }
    int incl = lds[t];
    int run = incl - tsum;           // exclusive prefix of this thread
    #pragma unroll
    for (int i = 0; i < SIT; ++i) {
        int idx = tbase + i;
        if (idx < n) rowOff[idx] = run;
        run += v[i];
    }
    if (t == SBS - 1) blockSums[blockIdx.x] = incl;
}

__global__ __launch_bounds__(SBS) void k_scan_sums(int* __restrict__ bs, int nb)
{
    __shared__ int lds[SBS];
    const int t = threadIdx.x;
    int v = (t < nb) ? bs[t] : 0;
    lds[t] = v;
    __syncthreads();
    #pragma unroll
    for (int off = 1; off < SBS; off <<= 1) {
        int y = (t >= off) ? lds[t - off] : 0;
        __syncthreads();
        lds[t] += y;
        __syncthreads();
    }
    if (t < nb) bs[t] = lds[t] - v;  // exclusive
}

__global__ __launch_bounds__(256) void k_scan_add(
    int* __restrict__ rowOff, int* __restrict__ cursor,
    const int* __restrict__ bs, int n, int ne)
{
    int i = blockIdx.x * 256 + threadIdx.x;
    if (i < n) {
        int v = rowOff[i] + bs[i / (SBS * SIT)];
        rowOff[i] = v;
        cursor[i] = v;
    }
    if (i == 0) rowOff[n] = ne;
}

__global__ __launch_bounds__(256) void k_place(
    const int* __restrict__ sidx, const int* __restrict__ didx,
    int* __restrict__ cursor, int* __restrict__ sorted, int ne)
{
    int e = blockIdx.x * 256 + threadIdx.x;
    if (e < ne) {
        int p = atomicAdd(&cursor[didx[e]], 1);
        sorted[p] = sidx[e];
    }
}

// ================= gather-aggregate (one wave per dst row) =================
// EPI 0: src fp32, out bf16 = relu(mean + bias)        (stage A, linearity trick)
// EPI 1: src bf16, out bf16 = mean                     (stage B)
// EPI 2: src bf16, out fp32 = w0*E + w1*mean           (stage C, fused finalize)
template<int EPI>
__global__ __launch_bounds__(256) void k_gather(
    const void* __restrict__ srcp, const int* __restrict__ sorted,
    const int* __restrict__ rowOff, const float* __restrict__ bias,
    const float* __restrict__ E, const float* __restrict__ alpha,
    void* __restrict__ out, int ndst)
{
    int d    = (blockIdx.x * 256 + threadIdx.x) >> 6;
    int lane = threadIdx.x & 63;
    if (d >= ndst) return;
    int e0 = rowOff[d], e1 = rowOff[d + 1];
    float ax = 0.f, ay = 0.f, az = 0.f, aw = 0.f;
    for (int e = e0; e < e1; ++e) {
        int s = sorted[e];
        if (EPI == 0) {
            float4 v = *(const float4*)((const float*)srcp + (size_t)s * DIM + lane * 4);
            ax += v.x; ay += v.y; az += v.z; aw += v.w;
        } else {
            ushort4 u = *(const ushort4*)((const unsigned short*)srcp + (size_t)s * DIM + lane * 4);
            ax += b2f(u.x); ay += b2f(u.y); az += b2f(u.z); aw += b2f(u.w);
        }
    }
    float inv = 1.0f / fmaxf((float)(e1 - e0), 1.0f);
    ax *= inv; ay *= inv; az *= inv; aw *= inv;
    if (EPI == 0) {
        float4 bv = *(const float4*)(bias + lane * 4);
        ax = fmaxf(ax + bv.x, 0.f); ay = fmaxf(ay + bv.y, 0.f);
        az = fmaxf(az + bv.z, 0.f); aw = fmaxf(aw + bv.w, 0.f);
        ushort4 o; o.x = f2b(ax); o.y = f2b(ay); o.z = f2b(az); o.w = f2b(aw);
        *(ushort4*)((unsigned short*)out + (size_t)d * DIM + lane * 4) = o;
    } else if (EPI == 1) {
        ushort4 o; o.x = f2b(ax); o.y = f2b(ay); o.z = f2b(az); o.w = f2b(aw);
        *(ushort4*)((unsigned short*)out + (size_t)d * DIM + lane * 4) = o;
    } else {
        float a0 = alpha[0], a1 = alpha[1];
        float mx = fmaxf(a0, a1);
        float x0 = expf(a0 - mx), x1 = expf(a1 - mx);
        float w0 = x0 / (x0 + x1), w1 = x1 / (x0 + x1);
        float4 ev = *(const float4*)(E + (size_t)d * DIM + lane * 4);
        float4 o;
        o.x = w0 * ev.x + w1 * ax; o.y = w0 * ev.y + w1 * ay;
        o.z = w0 * ev.z + w1 * az; o.w = w0 * ev.w + w1 * aw;
        *(float4*)((float*)out + (size_t)d * DIM + lane * 4) = o;
    }
}

// ================= tiled GEMM: C = act(A @ W^T [+ b]) =================
template<bool INBF16, bool OUTBF16, bool RELU, bool BIAS>
__global__ __launch_bounds__(256) void k_gemm(
    const void* __restrict__ Ap, const float* __restrict__ W,
    const float* __restrict__ bias, void* __restrict__ Cp, int M)
{
    __shared__ float As[16][68];
    __shared__ float Ws[16][68];
    const int tid  = threadIdx.x;
    const int m0   = blockIdx.x * 64;
    const int n0   = blockIdx.y * 64;
    const int lrow = tid >> 2;
    const int lk   = (tid & 3) * 4;
    const int arow = m0 + lrow;
    const int wrow = n0 + lrow;
    const int tm = (tid & 15) * 4;
    const int tn = (tid >> 4) * 4;
    float acc[4][4] = {};
    for (int k0 = 0; k0 < DIM; k0 += 16) {
        float4 av = make_float4(0.f, 0.f, 0.f, 0.f);
        if (arow < M) {
            if (INBF16) {
                ushort4 u = *(const ushort4*)((const unsigned short*)Ap + (size_t)arow * DIM + k0 + lk);
                av = make_float4(b2f(u.x), b2f(u.y), b2f(u.z), b2f(u.w));
            } else {
                av = *(const float4*)((const float*)Ap + (size_t)arow * DIM + k0 + lk);
            }
        }
        const float4 wv = *(const float4*)(W + (size_t)wrow * DIM + k0 + lk);
        __syncthreads();
        As[lk + 0][lrow] = av.x; As[lk + 1][lrow] = av.y;
        As[lk + 2][lrow] = av.z; As[lk + 3][lrow] = av.w;
        Ws[lk + 0][lrow] = wv.x; Ws[lk + 1][lrow] = wv.y;
        Ws[lk + 2][lrow] = wv.z; Ws[lk + 3][lrow] = wv.w;
        __syncthreads();
        #pragma unroll
        for (int k = 0; k < 16; ++k) {
            const float4 a = *(const float4*)&As[k][tm];
            const float4 w = *(const float4*)&Ws[k][tn];
            acc[0][0] += a.x * w.x; acc[0][1] += a.x * w.y; acc[0][2] += a.x * w.z; acc[0][3] += a.x * w.w;
            acc[1][0] += a.y * w.x; acc[1][1] += a.y * w.y; acc[1][2] += a.y * w.z; acc[1][3] += a.y * w.w;
            acc[2][0] += a.z * w.x; acc[2][1] += a.z * w.y; acc[2][2] += a.z * w.z; acc[2][3] += a.z * w.w;
            acc[3][0] += a.w * w.x; acc[3][1] += a.w * w.y; acc[3][2] += a.w * w.z; acc[3][3] += a.w * w.w;
        }
    }
    float4 bv = make_float4(0.f, 0.f, 0.f, 0.f);
    if (BIAS) bv = *(const float4*)(bias + n0 + tn);
    #pragma unroll
    for (int i = 0; i < 4; ++i) {
        int row = m0 + tm + i;
        if (row >= M) break;
        float4 o;
        o.x = acc[i][0] + bv.x; o.y = acc[i][1] + bv.y;
        o.z = acc[i][2] + bv.z; o.w = acc[i][3] + bv.w;
        if (RELU) {
            o.x = fmaxf(o.x, 0.f); o.y = fmaxf(o.y, 0.f);
            o.z = fmaxf(o.z, 0.f); o.w = fmaxf(o.w, 0.f);
        }
        if (OUTBF16) {
            ushort4 o4; o4.x = f2b(o.x); o4.y = f2b(o.y); o4.z = f2b(o.z); o4.w = f2b(o.w);
            *(ushort4*)((unsigned short*)Cp + (size_t)row * DIM + n0 + tn) = o4;
        } else {
            *(float4*)((float*)Cp + (size_t)row * DIM + n0 + tn) = o;
        }
    }
}

// ================= TransE score =================
__global__ __launch_bounds__(256) void k_score(
    const float* __restrict__ V, const float* __restrict__ R,
    const int* __restrict__ triples, const float* __restrict__ gamma,
    float* __restrict__ out, int B)
{
    int t    = (blockIdx.x * 256 + threadIdx.x) >> 6;
    int lane = threadIdx.x & 63;
    if (t >= B) return;
    int h  = triples[t * 3 + 0];
    int r  = triples[t * 3 + 1];
    int tl = triples[t * 3 + 2];
    float4 vh = *(const float4*)(V + (size_t)h  * DIM + lane * 4);
    float4 vr = *(const float4*)(R + (size_t)r  * DIM + lane * 4);
    float4 vt = *(const float4*)(V + (size_t)tl * DIM + lane * 4);
    float dx = vh.x + vr.x - vt.x;
    float dy = vh.y + vr.y - vt.y;
    float dz = vh.z + vr.z - vt.z;
    float dw = vh.w + vr.w - vt.w;
    float s = dx * dx + dy * dy + dz * dz + dw * dw;
    #pragma unroll
    for (int off = 32; off > 0; off >>= 1) s += __shfl_xor(s, off);
    if (lane == 0) out[t] = gamma[0] - sqrtf(s);
}

extern "C" void kernel_launch(void* const* d_in, const int* in_sizes, int n_in,
                              void* d_out, int out_size, void* d_ws, size_t ws_size,
                              hipStream_t stream)
{
    const float* E      = (const float*)d_in[0];
    const float* R      = (const float*)d_in[1];
    const float* lin2_w = (const float*)d_in[2];
    const float* lin2_b = (const float*)d_in[3];
    const float* lin3_w = (const float*)d_in[4];
    const float* lin3_b = (const float*)d_in[5];
    const float* t2e_w  = (const float*)d_in[6];
    const float* t2e_b  = (const float*)d_in[7];
    const float* alpha  = (const float*)d_in[8];
    const float* gamma  = (const float*)d_in[9];
    const int*   et     = (const int*)d_in[10];
    const int*   tt     = (const int*)d_in[11];
    const int*   etet   = (const int*)d_in[12];
    const int*   trip   = (const int*)d_in[13];

    const int NE   = in_sizes[0] / DIM;          // 100000
    const int ET   = in_sizes[10] / 2;           // 900000
    const int TT   = in_sizes[11] / 2;           // 600000
    const int ETET = in_sizes[12] / 2;           // 600000
    const int B    = in_sizes[13] / 3;           // 8192
    const int NT   = 300000, NTET = 150000;

    // ---- workspace layout (262 MB total) ----
    char* ws = (char*)d_ws;
    const size_t SZ1 = (size_t)NE * DIM * sizeof(float);          // 102.4 MB
    const size_t SZ2 = (size_t)NT * DIM * 2;                      // 153.6 MB
    float*          EW      = (float*)ws;                          // r1
    unsigned short* r1h     = (unsigned short*)ws;                 // r1 as bf16
    unsigned short* triEmb  = (unsigned short*)(ws + SZ1);         // r2
    unsigned short* tetEmb  = (unsigned short*)(ws + SZ1);         // r2 (after triEmb dead)
    float*          V       = (float*)(ws + SZ1);                  // r2 (after tetEmb dead)
    size_t off = SZ1 + SZ2;
    int* sorted   = (int*)(ws + off); off += (size_t)900000 * 4;
    int* rowOff   = (int*)(ws + off); off += (size_t)(NT + 1) * 4 + 12;
    int* cursor   = (int*)(ws + off); off += (size_t)NT * 4;
    int* blockSums= (int*)(ws + off); off += 256 * 4;
    if (ws_size < off) return;

    #define RUN_SORT(DIDX, SIDX, NEDGE, NDST)                                          \
        do {                                                                           \
            hipMemsetAsync(cursor, 0, (size_t)(NDST) * 4, stream);                     \
            k_count<<<((NEDGE) + 255) / 256, 256, 0, stream>>>((DIDX), cursor, (NEDGE));\
            int nb = ((NDST) + SBS * SIT - 1) / (SBS * SIT);                           \
            k_scan_block<<<nb, SBS, 0, stream>>>(cursor, rowOff, blockSums, (NDST));   \
            k_scan_sums<<<1, SBS, 0, stream>>>(blockSums, nb);                         \
            k_scan_add<<<((NDST) + 255) / 256, 256, 0, stream>>>(rowOff, cursor,       \
                                                blockSums, (NDST), (NEDGE));           \
            k_place<<<((NEDGE) + 255) / 256, 256, 0, stream>>>((SIDX), (DIDX), cursor, \
                                                sorted, (NEDGE));                      \
        } while (0)

    // ---- stage A: EW = E @ W2^T (no bias); triEmb = relu(mean_et(EW) + b2) ----
    dim3 gE((NE + 63) / 64, 4);
    k_gemm<false, false, false, false><<<gE, 256, 0, stream>>>(E, lin2_w, nullptr, EW, NE);
    RUN_SORT(et + ET, et, ET, NT);
    k_gather<0><<<(NT + 3) / 4, 256, 0, stream>>>(EW, sorted, rowOff, lin2_b,
                                                  nullptr, nullptr, triEmb, NT);

    // ---- stage B: tetAgg = mean_tt(triEmb); tetEmb = relu(tetAgg@W3^T+b3);
    //              tetProj = tetEmb @ t2e^T + b ----
    RUN_SORT(tt + TT, tt, TT, NTET);
    unsigned short* tetAgg  = r1h;                       // r1 (EW dead)
    k_gather<1><<<(NTET + 3) / 4, 256, 0, stream>>>(triEmb, sorted, rowOff, nullptr,
                                                    nullptr, nullptr, tetAgg, NTET);
    dim3 gT((NTET + 63) / 64, 4);
    k_gemm<true, true, true, true><<<gT, 256, 0, stream>>>(tetAgg, lin3_w, lin3_b, tetEmb, NTET);
    unsigned short* tetProj = r1h;                       // r1 (tetAgg dead)
    k_gemm<true, true, false, true><<<gT, 256, 0, stream>>>(tetEmb, t2e_w, t2e_b, tetProj, NTET);

    // ---- stage C: V = w0*E + w1*mean_etet(tetProj), fused ----
    RUN_SORT(etet, etet + ETET, ETET, NE);
    k_gather<2><<<(NE + 3) / 4, 256, 0, stream>>>(tetProj, sorted, rowOff, nullptr,
                                                  E, alpha, V, NE);

    // ---- stage D: TransE scores ----
    k_score<<<(B + 3) / 4, 256, 0, stream>>>(V, R, trip, gamma, (float*)d_out, B);
    #undef RUN_SORT
}

// Round 4
// 776.793 us; speedup vs baseline: 10.5997x; 1.6317x over previous
//
#include <hip/hip_runtime.h>
#include <hip/hip_bf16.h>
#include <math.h>

#define DIM 256
#define SBS 256
#define SIT 8            // scan items per thread -> 2048 per block

typedef __attribute__((ext_vector_type(8))) short          bf16x8;  // MFMA A/B frag
typedef __attribute__((ext_vector_type(8))) unsigned short u16x8;   // 16B bf16 copy
typedef __attribute__((ext_vector_type(4))) float          f32x4;   // MFMA acc

__device__ inline float b2f(unsigned short u) {
    union { unsigned int i; float f; } c; c.i = ((unsigned int)u) << 16; return c.f;
}
__device__ inline unsigned short f2b(float f) {
    __hip_bfloat16 h = __float2bfloat16(f);
    return *reinterpret_cast<unsigned short*>(&h);
}

// ================= fp32 -> bf16 cast =================
__global__ __launch_bounds__(256) void k_cast(
    const float* __restrict__ in, unsigned short* __restrict__ out, int n)
{
    int i = (blockIdx.x * 256 + threadIdx.x) * 4;
    if (i + 3 < n) {
        float4 v = *(const float4*)(in + i);
        ushort4 o; o.x = f2b(v.x); o.y = f2b(v.y); o.z = f2b(v.z); o.w = f2b(v.w);
        *(ushort4*)(out + i) = o;
    }
}

// ================= sort-by-destination machinery =================
__global__ __launch_bounds__(256) void k_count(
    const int* __restrict__ didx, int* __restrict__ cnt, int ne)
{
    int e = blockIdx.x * 256 + threadIdx.x;
    if (e < ne) atomicAdd(&cnt[didx[e]], 1);
}

__global__ __launch_bounds__(SBS) void k_scan_block(
    const int* __restrict__ cnt, int* __restrict__ rowOff,
    int* __restrict__ blockSums, int n)
{
    __shared__ int lds[SBS];
    const int t = threadIdx.x;
    const int tbase = blockIdx.x * SBS * SIT + t * SIT;
    int v[SIT]; int tsum = 0;
    #pragma unroll
    for (int i = 0; i < SIT; ++i) {
        int idx = tbase + i;
        v[i] = (idx < n) ? cnt[idx] : 0;
        tsum += v[i];
    }
    lds[t] = tsum;
    __syncthreads();
    #pragma unroll
    for (int off = 1; off < SBS; off <<= 1) {
        int y = (t >= off) ? lds[t - off] : 0;
        __syncthreads();
        lds[t] += y;
        __syncthreads();
    }
    int incl = lds[t];
    int run = incl - tsum;
    #pragma unroll
    for (int i = 0; i < SIT; ++i) {
        int idx = tbase + i;
        if (idx < n) rowOff[idx] = run;
        run += v[i];
    }
    if (t == SBS - 1) blockSums[blockIdx.x] = incl;
}

__global__ __launch_bounds__(SBS) void k_scan_sums(int* __restrict__ bs, int nb)
{
    __shared__ int lds[SBS];
    const int t = threadIdx.x;
    int v = (t < nb) ? bs[t] : 0;
    lds[t] = v;
    __syncthreads();
    #pragma unroll
    for (int off = 1; off < SBS; off <<= 1) {
        int y = (t >= off) ? lds[t - off] : 0;
        __syncthreads();
        lds[t] += y;
        __syncthreads();
    }
    if (t < nb) bs[t] = lds[t] - v;
}

__global__ __launch_bounds__(256) void k_scan_add(
    int* __restrict__ rowOff, int* __restrict__ cursor,
    const int* __restrict__ bs, int n, int ne)
{
    int i = blockIdx.x * 256 + threadIdx.x;
    if (i < n) {
        int v = rowOff[i] + bs[i / (SBS * SIT)];
        rowOff[i] = v;
        cursor[i] = v;
    }
    if (i == 0) rowOff[n] = ne;
}

__global__ __launch_bounds__(256) void k_place(
    const int* __restrict__ sidx, const int* __restrict__ didx,
    int* __restrict__ cursor, int* __restrict__ sorted, int ne)
{
    int e = blockIdx.x * 256 + threadIdx.x;
    if (e < ne) {
        int p = atomicAdd(&cursor[didx[e]], 1);
        sorted[p] = sidx[e];
    }
}

// ================= gather-aggregate (one wave per dst row), bf16 src =================
// EPI 0: out bf16 = relu(mean + bias)     (stage A, linearity trick)
// EPI 1: out bf16 = mean                  (stage B)
// EPI 2: out fp32 = w0*E + w1*mean        (stage C, fused finalize)
template<int EPI>
__global__ __launch_bounds__(256) void k_gather(
    const unsigned short* __restrict__ src, const int* __restrict__ sorted,
    const int* __restrict__ rowOff, const float* __restrict__ bias,
    const float* __restrict__ E, const float* __restrict__ alpha,
    void* __restrict__ out, int ndst)
{
    int d    = (blockIdx.x * 256 + threadIdx.x) >> 6;
    int lane = threadIdx.x & 63;
    if (d >= ndst) return;
    int e0 = rowOff[d], e1 = rowOff[d + 1];
    float ax = 0.f, ay = 0.f, az = 0.f, aw = 0.f;
    for (int e = e0; e < e1; ++e) {
        int s = sorted[e];
        ushort4 u = *(const ushort4*)(src + (size_t)s * DIM + lane * 4);
        ax += b2f(u.x); ay += b2f(u.y); az += b2f(u.z); aw += b2f(u.w);
    }
    float inv = 1.0f / fmaxf((float)(e1 - e0), 1.0f);
    ax *= inv; ay *= inv; az *= inv; aw *= inv;
    if (EPI == 0) {
        float4 bv = *(const float4*)(bias + lane * 4);
        ax = fmaxf(ax + bv.x, 0.f); ay = fmaxf(ay + bv.y, 0.f);
        az = fmaxf(az + bv.z, 0.f); aw = fmaxf(aw + bv.w, 0.f);
        ushort4 o; o.x = f2b(ax); o.y = f2b(ay); o.z = f2b(az); o.w = f2b(aw);
        *(ushort4*)((unsigned short*)out + (size_t)d * DIM + lane * 4) = o;
    } else if (EPI == 1) {
        ushort4 o; o.x = f2b(ax); o.y = f2b(ay); o.z = f2b(az); o.w = f2b(aw);
        *(ushort4*)((unsigned short*)out + (size_t)d * DIM + lane * 4) = o;
    } else {
        float a0 = alpha[0], a1 = alpha[1];
        float mx = fmaxf(a0, a1);
        float x0 = expf(a0 - mx), x1 = expf(a1 - mx);
        float w0 = x0 / (x0 + x1), w1 = x1 / (x0 + x1);
        float4 ev = *(const float4*)(E + (size_t)d * DIM + lane * 4);
        float4 o;
        o.x = w0 * ev.x + w1 * ax; o.y = w0 * ev.y + w1 * ay;
        o.z = w0 * ev.z + w1 * az; o.w = w0 * ev.w + w1 * aw;
        *(float4*)((float*)out + (size_t)d * DIM + lane * 4) = o;
    }
}

// ================= bf16 MFMA GEMM: C = act(A @ W^T [+ b]) =================
// A: [M,256] (fp32 if AF32 else bf16), W: [256,256] bf16 row-major (k-contig).
// C: [M,256] bf16. Tile 128x128, BK=64, 256 threads = 4 waves (2x2 of 64x64).
// LDS XOR-swizzle: byte ^= ((row&7)<<4) on both write and read (involution).
template<bool AF32, bool RELU, bool BIAS>
__global__ __launch_bounds__(256) void k_gemm_mfma(
    const void* __restrict__ Ap, const unsigned short* __restrict__ Wb,
    const float* __restrict__ bias, unsigned short* __restrict__ Cp, int M)
{
    __shared__ unsigned short As[128 * 64];
    __shared__ unsigned short Ws[128 * 64];
    const int tid  = threadIdx.x;
    const int m0   = blockIdx.x * 128;
    const int n0   = blockIdx.y * 128;
    const int wid  = tid >> 6, lane = tid & 63;
    const int wr   = wid >> 1, wc = wid & 1;
    const int sp   = tid & 7;        // 16B piece index within a 128B row
    const int sr   = tid >> 3;       // staging row 0..31 (+32*rr)
    const int fr   = lane & 15;
    const int fc   = lane >> 4;      // 0..3

    f32x4 acc[4][4] = {};
    for (int k0 = 0; k0 < DIM; k0 += 64) {
        __syncthreads();             // prior iter's reads done before overwrite
        #pragma unroll
        for (int rr = 0; rr < 4; ++rr) {
            int row = sr + rr * 32;
            int gm  = m0 + row; if (gm >= M) gm = M - 1;      // clamp tail
            unsigned off = row * 128 + ((sp * 16) ^ ((row & 7) << 4));
            if (AF32) {
                const float* g = (const float*)Ap + (size_t)gm * DIM + k0 + sp * 8;
                float4 lo = *(const float4*)g;
                float4 hi = *(const float4*)(g + 4);
                u16x8 v;
                v[0] = f2b(lo.x); v[1] = f2b(lo.y); v[2] = f2b(lo.z); v[3] = f2b(lo.w);
                v[4] = f2b(hi.x); v[5] = f2b(hi.y); v[6] = f2b(hi.z); v[7] = f2b(hi.w);
                *(u16x8*)((char*)As + off) = v;
            } else {
                const unsigned short* g = (const unsigned short*)Ap + (size_t)gm * DIM + k0 + sp * 8;
                *(u16x8*)((char*)As + off) = *(const u16x8*)g;
            }
            const unsigned short* gw = Wb + (size_t)(n0 + row) * DIM + k0 + sp * 8;
            *(u16x8*)((char*)Ws + off) = *(const u16x8*)gw;
        }
        __syncthreads();
        #pragma unroll
        for (int kk = 0; kk < 2; ++kk) {
            bf16x8 aF[4], bF[4];
            unsigned cb = kk * 64 + fc * 16;
            #pragma unroll
            for (int i = 0; i < 4; ++i) {
                int arow = wr * 64 + i * 16 + fr;
                aF[i] = *(const bf16x8*)((char*)As + arow * 128 + (cb ^ ((arow & 7) << 4)));
                int wrow = wc * 64 + i * 16 + fr;
                bF[i] = *(const bf16x8*)((char*)Ws + wrow * 128 + (cb ^ ((wrow & 7) << 4)));
            }
            #pragma unroll
            for (int i = 0; i < 4; ++i)
                #pragma unroll
                for (int j = 0; j < 4; ++j)
                    acc[i][j] = __builtin_amdgcn_mfma_f32_16x16x32_bf16(
                        aF[i], bF[j], acc[i][j], 0, 0, 0);
        }
    }
    // epilogue: C/D layout col = lane&15, row = (lane>>4)*4 + q
    const int cnb   = n0 + wc * 64 + fr;
    const int rbase = m0 + wr * 64 + fc * 4;
    #pragma unroll
    for (int j = 0; j < 4; ++j) {
        float bv = BIAS ? bias[cnb + j * 16] : 0.0f;
        #pragma unroll
        for (int i = 0; i < 4; ++i) {
            #pragma unroll
            for (int q = 0; q < 4; ++q) {
                int m = rbase + i * 16 + q;
                if (m < M) {
                    float v = acc[i][j][q] + bv;
                    if (RELU) v = fmaxf(v, 0.f);
                    Cp[(size_t)m * DIM + cnb + j * 16] = f2b(v);
                }
            }
        }
    }
}

// ================= TransE score =================
__global__ __launch_bounds__(256) void k_score(
    const float* __restrict__ V, const float* __restrict__ R,
    const int* __restrict__ triples, const float* __restrict__ gamma,
    float* __restrict__ out, int B)
{
    int t    = (blockIdx.x * 256 + threadIdx.x) >> 6;
    int lane = threadIdx.x & 63;
    if (t >= B) return;
    int h  = triples[t * 3 + 0];
    int r  = triples[t * 3 + 1];
    int tl = triples[t * 3 + 2];
    float4 vh = *(const float4*)(V + (size_t)h  * DIM + lane * 4);
    float4 vr = *(const float4*)(R + (size_t)r  * DIM + lane * 4);
    float4 vt = *(const float4*)(V + (size_t)tl * DIM + lane * 4);
    float dx = vh.x + vr.x - vt.x;
    float dy = vh.y + vr.y - vt.y;
    float dz = vh.z + vr.z - vt.z;
    float dw = vh.w + vr.w - vt.w;
    float s = dx * dx + dy * dy + dz * dz + dw * dw;
    #pragma unroll
    for (int off = 32; off > 0; off >>= 1) s += __shfl_xor(s, off);
    if (lane == 0) out[t] = gamma[0] - sqrtf(s);
}

extern "C" void kernel_launch(void* const* d_in, const int* in_sizes, int n_in,
                              void* d_out, int out_size, void* d_ws, size_t ws_size,
                              hipStream_t stream)
{
    const float* E      = (const float*)d_in[0];
    const float* R      = (const float*)d_in[1];
    const float* lin2_w = (const float*)d_in[2];
    const float* lin2_b = (const float*)d_in[3];
    const float* lin3_w = (const float*)d_in[4];
    const float* lin3_b = (const float*)d_in[5];
    const float* t2e_w  = (const float*)d_in[6];
    const float* t2e_b  = (const float*)d_in[7];
    const float* alpha  = (const float*)d_in[8];
    const float* gamma  = (const float*)d_in[9];
    const int*   et     = (const int*)d_in[10];
    const int*   tt     = (const int*)d_in[11];
    const int*   etet   = (const int*)d_in[12];
    const int*   trip   = (const int*)d_in[13];

    const int NE   = in_sizes[0] / DIM;          // 100000
    const int ET   = in_sizes[10] / 2;           // 900000
    const int TT   = in_sizes[11] / 2;           // 600000
    const int ETET = in_sizes[12] / 2;           // 600000
    const int B    = in_sizes[13] / 3;           // 8192
    const int NT   = 300000, NTET = 150000;

    // ---- workspace layout (~263 MB) ----
    char* ws = (char*)d_ws;
    const size_t P0  = 0;                                    // 102.4 MB region
    const size_t P1  = (size_t)NE * DIM * sizeof(float);     // 153.6 MB region
    const size_t SRT = P1 + (size_t)NT * DIM * 2;
    unsigned short* EW      = (unsigned short*)(ws + P0);                  // 51.2 MB
    unsigned short* tetAgg  = (unsigned short*)(ws + P0);                  // 76.8 MB (EW dead)
    float*          V       = (float*)(ws + P0);                           // 102.4 MB (tetAgg dead)
    unsigned short* triEmb  = (unsigned short*)(ws + P1);                  // 153.6 MB
    unsigned short* tetEmb  = (unsigned short*)(ws + P1);                  // 76.8 (triEmb dead)
    unsigned short* tetProj = (unsigned short*)(ws + P1) + (size_t)NTET * DIM;
    size_t off = SRT;
    int* sorted    = (int*)(ws + off); off += (size_t)900000 * 4;
    int* rowOff    = (int*)(ws + off); off += (size_t)(NT + 1) * 4 + 12;
    int* cursor    = (int*)(ws + off); off += (size_t)NT * 4;
    int* blockSums = (int*)(ws + off); off += 1024;
    unsigned short* W2b = (unsigned short*)(ws + off); off += 131072;
    unsigned short* W3b = (unsigned short*)(ws + off); off += 131072;
    unsigned short* Wtb = (unsigned short*)(ws + off); off += 131072;
    if (ws_size < off) return;

    #define RUN_SORT(DIDX, SIDX, NEDGE, NDST)                                          \
        do {                                                                           \
            hipMemsetAsync(cursor, 0, (size_t)(NDST) * 4, stream);                     \
            k_count<<<((NEDGE) + 255) / 256, 256, 0, stream>>>((DIDX), cursor, (NEDGE));\
            int nb = ((NDST) + SBS * SIT - 1) / (SBS * SIT);                           \
            k_scan_block<<<nb, SBS, 0, stream>>>(cursor, rowOff, blockSums, (NDST));   \
            k_scan_sums<<<1, SBS, 0, stream>>>(blockSums, nb);                         \
            k_scan_add<<<((NDST) + 255) / 256, 256, 0, stream>>>(rowOff, cursor,       \
                                                blockSums, (NDST), (NEDGE));           \
            k_place<<<((NEDGE) + 255) / 256, 256, 0, stream>>>((SIDX), (DIDX), cursor, \
                                                sorted, (NEDGE));                      \
        } while (0)

    // ---- weights -> bf16 ----
    k_cast<<<64, 256, 0, stream>>>(lin2_w, W2b, 65536);
    k_cast<<<64, 256, 0, stream>>>(lin3_w, W3b, 65536);
    k_cast<<<64, 256, 0, stream>>>(t2e_w,  Wtb, 65536);

    // ---- stage A: EW = E @ W2^T (fp32 A, on-the-fly bf16); triEmb = relu(mean+b2) ----
    dim3 gE((NE + 127) / 128, 2);
    k_gemm_mfma<true, false, false><<<gE, 256, 0, stream>>>(E, W2b, nullptr, EW, NE);
    RUN_SORT(et + ET, et, ET, NT);
    k_gather<0><<<(NT + 3) / 4, 256, 0, stream>>>(EW, sorted, rowOff, lin2_b,
                                                  nullptr, nullptr, triEmb, NT);

    // ---- stage B: tetAgg = mean_tt(triEmb); tetEmb = relu(tetAgg@W3^T+b3); tetProj ----
    RUN_SORT(tt + TT, tt, TT, NTET);
    k_gather<1><<<(NTET + 3) / 4, 256, 0, stream>>>(triEmb, sorted, rowOff, nullptr,
                                                    nullptr, nullptr, tetAgg, NTET);
    dim3 gT((NTET + 127) / 128, 2);
    k_gemm_mfma<false, true, true><<<gT, 256, 0, stream>>>(tetAgg, W3b, lin3_b, tetEmb, NTET);
    k_gemm_mfma<false, false, true><<<gT, 256, 0, stream>>>(tetEmb, Wtb, t2e_b, tetProj, NTET);

    // ---- stage C: V = w0*E + w1*mean_etet(tetProj), fused ----
    RUN_SORT(etet, etet + ETET, ETET, NE);
    k_gather<2><<<(NE + 3) / 4, 256, 0, stream>>>(tetProj, sorted, rowOff, nullptr,
                                                  E, alpha, V, NE);

    // ---- stage D: TransE scores ----
    k_score<<<(B + 3) / 4, 256, 0, stream>>>(V, R, trip, gamma, (float*)d_out, B);
    #undef RUN_SORT
}

// Round 5
// 598.239 us; speedup vs baseline: 13.7634x; 1.2985x over previous
//
#include <hip/hip_runtime.h>
#include <hip/hip_bf16.h>
#include <math.h>

#define DIM 256
#define SBS 256
#define SIT 8            // scan items per thread -> 2048 per block

typedef __attribute__((ext_vector_type(8))) short          bf16x8;  // MFMA A/B frag
typedef __attribute__((ext_vector_type(8))) unsigned short u16x8;   // 16B bf16 copy
typedef __attribute__((ext_vector_type(4))) float          f32x4;   // MFMA acc

__device__ inline float b2f(unsigned short u) {
    union { unsigned int i; float f; } c; c.i = ((unsigned int)u) << 16; return c.f;
}
__device__ inline unsigned short f2b(float f) {
    __hip_bfloat16 h = __float2bfloat16(f);
    return *reinterpret_cast<unsigned short*>(&h);
}

// ================= fp32 -> bf16 cast =================
__global__ __launch_bounds__(256) void k_cast(
    const float* __restrict__ in, unsigned short* __restrict__ out, int n)
{
    int i = (blockIdx.x * 256 + threadIdx.x) * 4;
    if (i + 3 < n) {
        float4 v = *(const float4*)(in + i);
        ushort4 o; o.x = f2b(v.x); o.y = f2b(v.y); o.z = f2b(v.z); o.w = f2b(v.w);
        *(ushort4*)(out + i) = o;
    }
}

// ================= mark needed entities from triples =================
__global__ __launch_bounds__(256) void k_mark(
    const int* __restrict__ trip, unsigned* __restrict__ bm, int B)
{
    int i = blockIdx.x * 256 + threadIdx.x;
    if (i < 2 * B) {
        int ent = trip[(i >> 1) * 3 + ((i & 1) ? 2 : 0)];
        atomicOr(&bm[ent >> 5], 1u << (ent & 31));
    }
}

// ================= sort-by-destination machinery =================
template<bool FILT>
__global__ __launch_bounds__(256) void k_count(
    const int* __restrict__ didx, const unsigned* __restrict__ bm,
    int* __restrict__ cnt, int ne)
{
    int e = blockIdx.x * 256 + threadIdx.x;
    if (e < ne) {
        int d = didx[e];
        if (FILT && !((bm[d >> 5] >> (d & 31)) & 1u)) return;
        atomicAdd(&cnt[d], 1);
    }
}

__global__ __launch_bounds__(SBS) void k_scan_block(
    const int* __restrict__ cnt, int* __restrict__ rowOff,
    int* __restrict__ blockSums, int n)
{
    __shared__ int lds[SBS];
    const int t = threadIdx.x;
    const int tbase = blockIdx.x * SBS * SIT + t * SIT;
    int v[SIT]; int tsum = 0;
    #pragma unroll
    for (int i = 0; i < SIT; ++i) {
        int idx = tbase + i;
        v[i] = (idx < n) ? cnt[idx] : 0;
        tsum += v[i];
    }
    lds[t] = tsum;
    __syncthreads();
    #pragma unroll
    for (int off = 1; off < SBS; off <<= 1) {
        int y = (t >= off) ? lds[t - off] : 0;
        __syncthreads();
        lds[t] += y;
        __syncthreads();
    }
    int incl = lds[t];
    int run = incl - tsum;
    #pragma unroll
    for (int i = 0; i < SIT; ++i) {
        int idx = tbase + i;
        if (idx < n) rowOff[idx] = run;
        run += v[i];
    }
    if (t == SBS - 1) blockSums[blockIdx.x] = incl;
}

__global__ __launch_bounds__(SBS) void k_scan_sums(int* __restrict__ bs, int nb)
{
    __shared__ int lds[SBS];
    const int t = threadIdx.x;
    int v = (t < nb) ? bs[t] : 0;
    lds[t] = v;
    __syncthreads();
    #pragma unroll
    for (int off = 1; off < SBS; off <<= 1) {
        int y = (t >= off) ? lds[t - off] : 0;
        __syncthreads();
        lds[t] += y;
        __syncthreads();
    }
    if (t < nb) {
        bs[t] = lds[t] - v;                    // exclusive
        if (t == nb - 1) bs[nb] = lds[t];      // total placed edges
    }
}

__global__ __launch_bounds__(256) void k_scan_add(
    int* __restrict__ rowOff, int* __restrict__ cursor,
    const int* __restrict__ bs, int n, int nb)
{
    int i = blockIdx.x * 256 + threadIdx.x;
    if (i < n) {
        int v = rowOff[i] + bs[i / (SBS * SIT)];
        rowOff[i] = v;
        cursor[i] = v;
    }
    if (i == 0) rowOff[n] = bs[nb];
}

template<bool FILT>
__global__ __launch_bounds__(256) void k_place(
    const int* __restrict__ sidx, const int* __restrict__ didx,
    const unsigned* __restrict__ bm, int* __restrict__ cursor,
    int* __restrict__ sorted, int ne)
{
    int e = blockIdx.x * 256 + threadIdx.x;
    if (e < ne) {
        int d = didx[e];
        if (FILT && !((bm[d >> 5] >> (d & 31)) & 1u)) return;
        int p = atomicAdd(&cursor[d], 1);
        sorted[p] = sidx[e];
    }
}

// ================= gather-aggregate (one wave per dst row), bf16 src =================
// 4-wide batched loads: 4 independent row loads in flight per wave.
// EPI 0: out bf16 = relu(mean + bias)     (stage A, linearity trick)
// EPI 1: out bf16 = mean                  (stage B)
// EPI 2: out fp32 = w0*E + w1*mean        (stage C, fused finalize, bitmap-filtered)
template<int EPI>
__global__ __launch_bounds__(256) void k_gather(
    const unsigned short* __restrict__ src, const int* __restrict__ sorted,
    const int* __restrict__ rowOff, const float* __restrict__ bias,
    const float* __restrict__ E, const float* __restrict__ alpha,
    const unsigned* __restrict__ bm, void* __restrict__ out, int ndst)
{
    int d    = (blockIdx.x * 256 + threadIdx.x) >> 6;
    int lane = threadIdx.x & 63;
    if (d >= ndst) return;
    if (EPI == 2 && !((bm[d >> 5] >> (d & 31)) & 1u)) return;
    int e0 = rowOff[d], e1 = rowOff[d + 1];
    float ax = 0.f, ay = 0.f, az = 0.f, aw = 0.f;
    for (int base = e0; base < e1; base += 4) {
        #pragma unroll
        for (int j = 0; j < 4; ++j) {
            int ee = base + j;
            int ec = (ee < e1) ? ee : (e1 - 1);
            int s  = sorted[ec];
            ushort4 u = *(const ushort4*)(src + (size_t)s * DIM + lane * 4);
            float g = (ee < e1) ? 1.0f : 0.0f;
            ax += g * b2f(u.x); ay += g * b2f(u.y);
            az += g * b2f(u.z); aw += g * b2f(u.w);
        }
    }
    float inv = 1.0f / fmaxf((float)(e1 - e0), 1.0f);
    ax *= inv; ay *= inv; az *= inv; aw *= inv;
    if (EPI == 0) {
        float4 bv = *(const float4*)(bias + lane * 4);
        ax = fmaxf(ax + bv.x, 0.f); ay = fmaxf(ay + bv.y, 0.f);
        az = fmaxf(az + bv.z, 0.f); aw = fmaxf(aw + bv.w, 0.f);
        ushort4 o; o.x = f2b(ax); o.y = f2b(ay); o.z = f2b(az); o.w = f2b(aw);
        *(ushort4*)((unsigned short*)out + (size_t)d * DIM + lane * 4) = o;
    } else if (EPI == 1) {
        ushort4 o; o.x = f2b(ax); o.y = f2b(ay); o.z = f2b(az); o.w = f2b(aw);
        *(ushort4*)((unsigned short*)out + (size_t)d * DIM + lane * 4) = o;
    } else {
        float a0 = alpha[0], a1 = alpha[1];
        float mx = fmaxf(a0, a1);
        float x0 = expf(a0 - mx), x1 = expf(a1 - mx);
        float w0 = x0 / (x0 + x1), w1 = x1 / (x0 + x1);
        float4 ev = *(const float4*)(E + (size_t)d * DIM + lane * 4);
        float4 o;
        o.x = w0 * ev.x + w1 * ax; o.y = w0 * ev.y + w1 * ay;
        o.z = w0 * ev.z + w1 * az; o.w = w0 * ev.w + w1 * aw;
        *(float4*)((float*)out + (size_t)d * DIM + lane * 4) = o;
    }
}

// ================= bf16 MFMA GEMM: C = act(A @ W^T [+ b]) =================
// Tile 128x128, BK=64, 256 threads = 4 waves (2x2 of 64x64).
// LDS XOR-swizzle: byte ^= ((row&7)<<4) on both write and read (involution).
template<bool AF32, bool RELU, bool BIAS>
__global__ __launch_bounds__(256) void k_gemm_mfma(
    const void* __restrict__ Ap, const unsigned short* __restrict__ Wb,
    const float* __restrict__ bias, unsigned short* __restrict__ Cp, int M)
{
    __shared__ unsigned short As[128 * 64];
    __shared__ unsigned short Ws[128 * 64];
    const int tid  = threadIdx.x;
    const int m0   = blockIdx.x * 128;
    const int n0   = blockIdx.y * 128;
    const int wid  = tid >> 6, lane = tid & 63;
    const int wr   = wid >> 1, wc = wid & 1;
    const int sp   = tid & 7;
    const int sr   = tid >> 3;
    const int fr   = lane & 15;
    const int fc   = lane >> 4;

    f32x4 acc[4][4] = {};
    for (int k0 = 0; k0 < DIM; k0 += 64) {
        __syncthreads();
        #pragma unroll
        for (int rr = 0; rr < 4; ++rr) {
            int row = sr + rr * 32;
            int gm  = m0 + row; if (gm >= M) gm = M - 1;
            unsigned off = row * 128 + ((sp * 16) ^ ((row & 7) << 4));
            if (AF32) {
                const float* g = (const float*)Ap + (size_t)gm * DIM + k0 + sp * 8;
                float4 lo = *(const float4*)g;
                float4 hi = *(const float4*)(g + 4);
                u16x8 v;
                v[0] = f2b(lo.x); v[1] = f2b(lo.y); v[2] = f2b(lo.z); v[3] = f2b(lo.w);
                v[4] = f2b(hi.x); v[5] = f2b(hi.y); v[6] = f2b(hi.z); v[7] = f2b(hi.w);
                *(u16x8*)((char*)As + off) = v;
            } else {
                const unsigned short* g = (const unsigned short*)Ap + (size_t)gm * DIM + k0 + sp * 8;
                *(u16x8*)((char*)As + off) = *(const u16x8*)g;
            }
            const unsigned short* gw = Wb + (size_t)(n0 + row) * DIM + k0 + sp * 8;
            *(u16x8*)((char*)Ws + off) = *(const u16x8*)gw;
        }
        __syncthreads();
        #pragma unroll
        for (int kk = 0; kk < 2; ++kk) {
            bf16x8 aF[4], bF[4];
            unsigned cb = kk * 64 + fc * 16;
            #pragma unroll
            for (int i = 0; i < 4; ++i) {
                int arow = wr * 64 + i * 16 + fr;
                aF[i] = *(const bf16x8*)((char*)As + arow * 128 + (cb ^ ((arow & 7) << 4)));
                int wrow = wc * 64 + i * 16 + fr;
                bF[i] = *(const bf16x8*)((char*)Ws + wrow * 128 + (cb ^ ((wrow & 7) << 4)));
            }
            #pragma unroll
            for (int i = 0; i < 4; ++i)
                #pragma unroll
                for (int j = 0; j < 4; ++j)
                    acc[i][j] = __builtin_amdgcn_mfma_f32_16x16x32_bf16(
                        aF[i], bF[j], acc[i][j], 0, 0, 0);
        }
    }
    const int cnb   = n0 + wc * 64 + fr;
    const int rbase = m0 + wr * 64 + fc * 4;
    #pragma unroll
    for (int j = 0; j < 4; ++j) {
        float bv = BIAS ? bias[cnb + j * 16] : 0.0f;
        #pragma unroll
        for (int i = 0; i < 4; ++i) {
            #pragma unroll
            for (int q = 0; q < 4; ++q) {
                int m = rbase + i * 16 + q;
                if (m < M) {
                    float v = acc[i][j][q] + bv;
                    if (RELU) v = fmaxf(v, 0.f);
                    Cp[(size_t)m * DIM + cnb + j * 16] = f2b(v);
                }
            }
        }
    }
}

// ================= TransE score =================
__global__ __launch_bounds__(256) void k_score(
    const float* __restrict__ V, const float* __restrict__ R,
    const int* __restrict__ triples, const float* __restrict__ gamma,
    float* __restrict__ out, int B)
{
    int t    = (blockIdx.x * 256 + threadIdx.x) >> 6;
    int lane = threadIdx.x & 63;
    if (t >= B) return;
    int h  = triples[t * 3 + 0];
    int r  = triples[t * 3 + 1];
    int tl = triples[t * 3 + 2];
    float4 vh = *(const float4*)(V + (size_t)h  * DIM + lane * 4);
    float4 vr = *(const float4*)(R + (size_t)r  * DIM + lane * 4);
    float4 vt = *(const float4*)(V + (size_t)tl * DIM + lane * 4);
    float dx = vh.x + vr.x - vt.x;
    float dy = vh.y + vr.y - vt.y;
    float dz = vh.z + vr.z - vt.z;
    float dw = vh.w + vr.w - vt.w;
    float s = dx * dx + dy * dy + dz * dz + dw * dw;
    #pragma unroll
    for (int off = 32; off > 0; off >>= 1) s += __shfl_xor(s, off);
    if (lane == 0) out[t] = gamma[0] - sqrtf(s);
}

extern "C" void kernel_launch(void* const* d_in, const int* in_sizes, int n_in,
                              void* d_out, int out_size, void* d_ws, size_t ws_size,
                              hipStream_t stream)
{
    const float* E      = (const float*)d_in[0];
    const float* R      = (const float*)d_in[1];
    const float* lin2_w = (const float*)d_in[2];
    const float* lin2_b = (const float*)d_in[3];
    const float* lin3_w = (const float*)d_in[4];
    const float* lin3_b = (const float*)d_in[5];
    const float* t2e_w  = (const float*)d_in[6];
    const float* t2e_b  = (const float*)d_in[7];
    const float* alpha  = (const float*)d_in[8];
    const float* gamma  = (const float*)d_in[9];
    const int*   et     = (const int*)d_in[10];
    const int*   tt     = (const int*)d_in[11];
    const int*   etet   = (const int*)d_in[12];
    const int*   trip   = (const int*)d_in[13];

    const int NE   = in_sizes[0] / DIM;          // 100000
    const int ET   = in_sizes[10] / 2;           // 900000
    const int TT   = in_sizes[11] / 2;           // 600000
    const int ETET = in_sizes[12] / 2;           // 600000
    const int B    = in_sizes[13] / 3;           // 8192
    const int NT   = 300000, NTET = 150000;

    // ---- workspace layout (~263 MB) ----
    char* ws = (char*)d_ws;
    const size_t P0  = 0;
    const size_t P1  = (size_t)NE * DIM * sizeof(float);
    const size_t SRT = P1 + (size_t)NT * DIM * 2;
    unsigned short* EW      = (unsigned short*)(ws + P0);
    unsigned short* tetAgg  = (unsigned short*)(ws + P0);
    float*          V       = (float*)(ws + P0);
    unsigned short* triEmb  = (unsigned short*)(ws + P1);
    unsigned short* tetEmb  = (unsigned short*)(ws + P1);
    unsigned short* tetProj = (unsigned short*)(ws + P1) + (size_t)NTET * DIM;
    size_t off = SRT;
    int* sorted    = (int*)(ws + off); off += (size_t)900000 * 4;
    int* rowOff    = (int*)(ws + off); off += (size_t)(NT + 1) * 4 + 12;
    int* cursor    = (int*)(ws + off); off += (size_t)NT * 4;
    int* blockSums = (int*)(ws + off); off += 1040;
    unsigned short* W2b = (unsigned short*)(ws + off); off += 131072;
    unsigned short* W3b = (unsigned short*)(ws + off); off += 131072;
    unsigned short* Wtb = (unsigned short*)(ws + off); off += 131072;
    unsigned* bm   = (unsigned*)(ws + off); off += ((size_t)(NE + 31) / 32) * 4;
    if (ws_size < off) return;

    #define RUN_SORT(DIDX, SIDX, NEDGE, NDST, FILTC)                                   \
        do {                                                                           \
            hipMemsetAsync(cursor, 0, (size_t)(NDST) * 4, stream);                     \
            k_count<FILTC><<<((NEDGE) + 255) / 256, 256, 0, stream>>>((DIDX), bm,      \
                                                cursor, (NEDGE));                      \
            int nb = ((NDST) + SBS * SIT - 1) / (SBS * SIT);                           \
            k_scan_block<<<nb, SBS, 0, stream>>>(cursor, rowOff, blockSums, (NDST));   \
            k_scan_sums<<<1, SBS, 0, stream>>>(blockSums, nb);                         \
            k_scan_add<<<((NDST) + 255) / 256, 256, 0, stream>>>(rowOff, cursor,       \
                                                blockSums, (NDST), nb);                \
            k_place<FILTC><<<((NEDGE) + 255) / 256, 256, 0, stream>>>((SIDX), (DIDX),  \
                                                bm, cursor, sorted, (NEDGE));          \
        } while (0)

    // ---- weights -> bf16 ----
    k_cast<<<64, 256, 0, stream>>>(lin2_w, W2b, 65536);
    k_cast<<<64, 256, 0, stream>>>(lin3_w, W3b, 65536);
    k_cast<<<64, 256, 0, stream>>>(t2e_w,  Wtb, 65536);

    // ---- stage A: EW = E @ W2^T; triEmb = relu(mean_et(EW) + b2) ----
    dim3 gE((NE + 127) / 128, 2);
    k_gemm_mfma<true, false, false><<<gE, 256, 0, stream>>>(E, W2b, nullptr, EW, NE);
    RUN_SORT(et + ET, et, ET, NT, false);
    k_gather<0><<<(NT + 3) / 4, 256, 0, stream>>>(EW, sorted, rowOff, lin2_b,
                                                  nullptr, nullptr, nullptr, triEmb, NT);

    // ---- stage B: tetAgg = mean_tt(triEmb); tetEmb = relu(tetAgg@W3^T+b3); tetProj ----
    RUN_SORT(tt + TT, tt, TT, NTET, false);
    k_gather<1><<<(NTET + 3) / 4, 256, 0, stream>>>(triEmb, sorted, rowOff, nullptr,
                                                    nullptr, nullptr, nullptr, tetAgg, NTET);
    dim3 gT((NTET + 127) / 128, 2);
    k_gemm_mfma<false, true, true><<<gT, 256, 0, stream>>>(tetAgg, W3b, lin3_b, tetEmb, NTET);
    k_gemm_mfma<false, false, true><<<gT, 256, 0, stream>>>(tetEmb, Wtb, t2e_b, tetProj, NTET);

    // ---- stage C: V = w0*E + w1*mean_etet(tetProj), only for entities in triples ----
    hipMemsetAsync(bm, 0, ((size_t)(NE + 31) / 32) * 4, stream);
    k_mark<<<(2 * B + 255) / 256, 256, 0, stream>>>(trip, bm, B);
    RUN_SORT(etet, etet + ETET, ETET, NE, true);
    k_gather<2><<<(NE + 3) / 4, 256, 0, stream>>>(tetProj, sorted, rowOff, nullptr,
                                                  E, alpha, bm, V, NE);

    // ---- stage D: TransE scores ----
    k_score<<<(B + 3) / 4, 256, 0, stream>>>(V, R, trip, gamma, (float*)d_out, B);
    #undef RUN_SORT
}

// Round 6
// 479.215 us; speedup vs baseline: 17.1818x; 1.2484x over previous
//
#include <hip/hip_runtime.h>
#include <hip/hip_bf16.h>
#include <math.h>

#define DIM 256
#define SBS 256
#define SIT 16           // scan items per thread -> 4096 per block
#define NT   300000
#define NTET 150000

typedef __attribute__((ext_vector_type(8))) short          bf16x8;
typedef __attribute__((ext_vector_type(8))) unsigned short u16x8;
typedef __attribute__((ext_vector_type(4))) float          f32x4;

__device__ inline float b2f(unsigned short u) {
    union { unsigned int i; float f; } c; c.i = ((unsigned int)u) << 16; return c.f;
}
__device__ inline unsigned short f2b(float f) {
    __hip_bfloat16 h = __float2bfloat16(f);
    return *reinterpret_cast<unsigned short*>(&h);
}
__device__ inline bool bmget(const unsigned* bm, int i) {
    return (bm[i >> 5] >> (i & 31)) & 1u;
}

// ================= fused weight cast: 3x [256,256] fp32 -> bf16 =================
__global__ __launch_bounds__(256) void k_cast3(
    const float* __restrict__ w2, const float* __restrict__ w3,
    const float* __restrict__ wt, unsigned short* __restrict__ out)
{
    int i = (blockIdx.x * 256 + threadIdx.x) * 4;      // < 196608
    const float* src; int l;
    if (i < 65536)       { src = w2; l = i; }
    else if (i < 131072) { src = w3; l = i - 65536; }
    else                 { src = wt; l = i - 131072; }
    float4 v = *(const float4*)(src + l);
    ushort4 o; o.x = f2b(v.x); o.y = f2b(v.y); o.z = f2b(v.z); o.w = f2b(v.w);
    *(ushort4*)(out + i) = o;
}

// ================= bitmap marking =================
__global__ __launch_bounds__(256) void k_mark(
    const int* __restrict__ trip, unsigned* __restrict__ bm, int B)
{
    int i = blockIdx.x * 256 + threadIdx.x;
    if (i < 2 * B) {
        int ent = trip[(i >> 1) * 3 + ((i & 1) ? 2 : 0)];
        atomicOr(&bm[ent >> 5], 1u << (ent & 31));
    }
}

// mark bmOut[mi[e]] where bmIn[ci[e]]
__global__ __launch_bounds__(256) void k_markf(
    const int* __restrict__ mi, const int* __restrict__ ci,
    const unsigned* __restrict__ bmIn, unsigned* __restrict__ bmOut, int n)
{
    int e = blockIdx.x * 256 + threadIdx.x;
    if (e < n && bmget(bmIn, ci[e])) {
        int m = mi[e];
        atomicOr(&bmOut[m >> 5], 1u << (m & 31));
    }
}

// ================= concatenated count / scan / place =================
__global__ __launch_bounds__(256) void k_count_all(
    const int* __restrict__ et, const int* __restrict__ tt, const int* __restrict__ etet,
    const unsigned* __restrict__ bmTri, const unsigned* __restrict__ bmTet,
    const unsigned* __restrict__ bmEnt, int* __restrict__ cnt,
    int ET, int TT, int ETET)
{
    int e = blockIdx.x * 256 + threadIdx.x;
    if (e < ET) {
        int d = et[ET + e];
        if (bmget(bmTri, d)) atomicAdd(&cnt[d], 1);
    } else if (e < ET + TT) {
        int i = e - ET;
        int d = tt[TT + i];
        if (bmget(bmTet, d)) atomicAdd(&cnt[NT + d], 1);
    } else if (e < ET + TT + ETET) {
        int i = e - ET - TT;
        int d = etet[i];
        if (bmget(bmEnt, d)) atomicAdd(&cnt[NT + NTET + d], 1);
    }
}

__global__ __launch_bounds__(SBS) void k_scan_block(
    const int* __restrict__ cnt, int* __restrict__ rowOff,
    int* __restrict__ blockSums, int n)
{
    __shared__ int lds[SBS];
    const int t = threadIdx.x;
    const int tbase = blockIdx.x * SBS * SIT + t * SIT;
    int v[SIT]; int tsum = 0;
    #pragma unroll
    for (int i = 0; i < SIT; ++i) {
        int idx = tbase + i;
        v[i] = (idx < n) ? cnt[idx] : 0;
        tsum += v[i];
    }
    lds[t] = tsum;
    __syncthreads();
    #pragma unroll
    for (int off = 1; off < SBS; off <<= 1) {
        int y = (t >= off) ? lds[t - off] : 0;
        __syncthreads();
        lds[t] += y;
        __syncthreads();
    }
    int incl = lds[t];
    int run = incl - tsum;
    #pragma unroll
    for (int i = 0; i < SIT; ++i) {
        int idx = tbase + i;
        if (idx < n) rowOff[idx] = run;
        run += v[i];
    }
    if (t == SBS - 1) blockSums[blockIdx.x] = incl;
}

__global__ __launch_bounds__(SBS) void k_scan_sums(int* __restrict__ bs, int nb)
{
    __shared__ int lds[SBS];
    const int t = threadIdx.x;
    int v = (t < nb) ? bs[t] : 0;
    lds[t] = v;
    __syncthreads();
    #pragma unroll
    for (int off = 1; off < SBS; off <<= 1) {
        int y = (t >= off) ? lds[t - off] : 0;
        __syncthreads();
        lds[t] += y;
        __syncthreads();
    }
    if (t < nb) {
        bs[t] = lds[t] - v;
        if (t == nb - 1) bs[nb] = lds[t];
    }
}

__global__ __launch_bounds__(256) void k_scan_add(
    int* __restrict__ rowOff, int* __restrict__ cursor,
    const int* __restrict__ bs, int n, int nb)
{
    int i = blockIdx.x * 256 + threadIdx.x;
    if (i < n) {
        int v = rowOff[i] + bs[i / (SBS * SIT)];
        rowOff[i] = v;
        cursor[i] = v;
    }
    if (i == 0) rowOff[n] = bs[nb];
}

__global__ __launch_bounds__(256) void k_place_all(
    const int* __restrict__ et, const int* __restrict__ tt, const int* __restrict__ etet,
    const unsigned* __restrict__ bmTri, const unsigned* __restrict__ bmTet,
    const unsigned* __restrict__ bmEnt, int* __restrict__ cursor,
    int* __restrict__ sorted, int ET, int TT, int ETET)
{
    int e = blockIdx.x * 256 + threadIdx.x;
    if (e < ET) {
        int d = et[ET + e];
        if (bmget(bmTri, d)) sorted[atomicAdd(&cursor[d], 1)] = et[e];
    } else if (e < ET + TT) {
        int i = e - ET;
        int d = tt[TT + i];
        if (bmget(bmTet, d)) sorted[atomicAdd(&cursor[NT + d], 1)] = tt[i];
    } else if (e < ET + TT + ETET) {
        int i = e - ET - TT;
        int d = etet[i];
        if (bmget(bmEnt, d)) sorted[atomicAdd(&cursor[NT + NTET + d], 1)] = etet[ETET + i];
    }
}

// ================= gather-aggregate (one wave per dst row), bf16 src =================
// EPI 0: out bf16 = relu(mean + bias)     (stage A; skip if !bmTri)
// EPI 1: out bf16 = mean                  (stage B; skip if !bmTet)
// EPI 2: out fp32 = w0*E + w1*mean        (stage C; skip if !bmEnt)
template<int EPI>
__global__ __launch_bounds__(256) void k_gather(
    const unsigned short* __restrict__ src, const int* __restrict__ sorted,
    const int* __restrict__ rowOff, const float* __restrict__ bias,
    const float* __restrict__ E, const float* __restrict__ alpha,
    const unsigned* __restrict__ bm, void* __restrict__ out, int ndst)
{
    int d    = (blockIdx.x * 256 + threadIdx.x) >> 6;
    int lane = threadIdx.x & 63;
    if (d >= ndst) return;
    if (!bmget(bm, d)) return;
    int e0 = rowOff[d], e1 = rowOff[d + 1];
    float ax = 0.f, ay = 0.f, az = 0.f, aw = 0.f;
    int base = e0;
    for (; base + 4 <= e1; base += 4) {
        #pragma unroll
        for (int j = 0; j < 4; ++j) {
            int s = sorted[base + j];
            ushort4 u = *(const ushort4*)(src + (size_t)s * DIM + lane * 4);
            ax += b2f(u.x); ay += b2f(u.y); az += b2f(u.z); aw += b2f(u.w);
        }
    }
    if (base < e1) {
        #pragma unroll
        for (int j = 0; j < 4; ++j) {
            int ee = base + j;
            int ec = (ee < e1) ? ee : (e1 - 1);
            int s  = sorted[ec];
            ushort4 u = *(const ushort4*)(src + (size_t)s * DIM + lane * 4);
            float g = (ee < e1) ? 1.0f : 0.0f;
            ax += g * b2f(u.x); ay += g * b2f(u.y);
            az += g * b2f(u.z); aw += g * b2f(u.w);
        }
    }
    float inv = 1.0f / fmaxf((float)(e1 - e0), 1.0f);
    ax *= inv; ay *= inv; az *= inv; aw *= inv;
    if (EPI == 0) {
        float4 bv = *(const float4*)(bias + lane * 4);
        ax = fmaxf(ax + bv.x, 0.f); ay = fmaxf(ay + bv.y, 0.f);
        az = fmaxf(az + bv.z, 0.f); aw = fmaxf(aw + bv.w, 0.f);
        ushort4 o; o.x = f2b(ax); o.y = f2b(ay); o.z = f2b(az); o.w = f2b(aw);
        *(ushort4*)((unsigned short*)out + (size_t)d * DIM + lane * 4) = o;
    } else if (EPI == 1) {
        ushort4 o; o.x = f2b(ax); o.y = f2b(ay); o.z = f2b(az); o.w = f2b(aw);
        *(ushort4*)((unsigned short*)out + (size_t)d * DIM + lane * 4) = o;
    } else {
        float a0 = alpha[0], a1 = alpha[1];
        float mx = fmaxf(a0, a1);
        float x0 = expf(a0 - mx), x1 = expf(a1 - mx);
        float w0 = x0 / (x0 + x1), w1 = x1 / (x0 + x1);
        float4 ev = *(const float4*)(E + (size_t)d * DIM + lane * 4);
        float4 o;
        o.x = w0 * ev.x + w1 * ax; o.y = w0 * ev.y + w1 * ay;
        o.z = w0 * ev.z + w1 * az; o.w = w0 * ev.w + w1 * aw;
        *(float4*)((float*)out + (size_t)d * DIM + lane * 4) = o;
    }
}

// ================= bf16 MFMA GEMM: C = act(A @ W^T [+ b]) =================
// Tile 128x128, BK=64, 256 threads = 4 waves (2x2 of 64x64).
// LDS XOR-swizzle: byte ^= ((row&7)<<4) on both write and read (involution).
template<bool AF32, bool RELU, bool BIAS>
__global__ __launch_bounds__(256) void k_gemm_mfma(
    const void* __restrict__ Ap, const unsigned short* __restrict__ Wb,
    const float* __restrict__ bias, unsigned short* __restrict__ Cp, int M)
{
    __shared__ unsigned short As[128 * 64];
    __shared__ unsigned short Ws[128 * 64];
    const int tid  = threadIdx.x;
    const int m0   = blockIdx.x * 128;
    const int n0   = blockIdx.y * 128;
    const int wid  = tid >> 6, lane = tid & 63;
    const int wr   = wid >> 1, wc = wid & 1;
    const int sp   = tid & 7;
    const int sr   = tid >> 3;
    const int fr   = lane & 15;
    const int fc   = lane >> 4;

    f32x4 acc[4][4] = {};
    for (int k0 = 0; k0 < DIM; k0 += 64) {
        __syncthreads();
        #pragma unroll
        for (int rr = 0; rr < 4; ++rr) {
            int row = sr + rr * 32;
            int gm  = m0 + row; if (gm >= M) gm = M - 1;
            unsigned off = row * 128 + ((sp * 16) ^ ((row & 7) << 4));
            if (AF32) {
                const float* g = (const float*)Ap + (size_t)gm * DIM + k0 + sp * 8;
                float4 lo = *(const float4*)g;
                float4 hi = *(const float4*)(g + 4);
                u16x8 v;
                v[0] = f2b(lo.x); v[1] = f2b(lo.y); v[2] = f2b(lo.z); v[3] = f2b(lo.w);
                v[4] = f2b(hi.x); v[5] = f2b(hi.y); v[6] = f2b(hi.z); v[7] = f2b(hi.w);
                *(u16x8*)((char*)As + off) = v;
            } else {
                const unsigned short* g = (const unsigned short*)Ap + (size_t)gm * DIM + k0 + sp * 8;
                *(u16x8*)((char*)As + off) = *(const u16x8*)g;
            }
            const unsigned short* gw = Wb + (size_t)(n0 + row) * DIM + k0 + sp * 8;
            *(u16x8*)((char*)Ws + off) = *(const u16x8*)gw;
        }
        __syncthreads();
        #pragma unroll
        for (int kk = 0; kk < 2; ++kk) {
            bf16x8 aF[4], bF[4];
            unsigned cb = kk * 64 + fc * 16;
            #pragma unroll
            for (int i = 0; i < 4; ++i) {
                int arow = wr * 64 + i * 16 + fr;
                aF[i] = *(const bf16x8*)((char*)As + arow * 128 + (cb ^ ((arow & 7) << 4)));
                int wrow = wc * 64 + i * 16 + fr;
                bF[i] = *(const bf16x8*)((char*)Ws + wrow * 128 + (cb ^ ((wrow & 7) << 4)));
            }
            #pragma unroll
            for (int i = 0; i < 4; ++i)
                #pragma unroll
                for (int j = 0; j < 4; ++j)
                    acc[i][j] = __builtin_amdgcn_mfma_f32_16x16x32_bf16(
                        aF[i], bF[j], acc[i][j], 0, 0, 0);
        }
    }
    const int cnb   = n0 + wc * 64 + fr;
    const int rbase = m0 + wr * 64 + fc * 4;
    #pragma unroll
    for (int j = 0; j < 4; ++j) {
        float bv = BIAS ? bias[cnb + j * 16] : 0.0f;
        #pragma unroll
        for (int i = 0; i < 4; ++i) {
            #pragma unroll
            for (int q = 0; q < 4; ++q) {
                int m = rbase + i * 16 + q;
                if (m < M) {
                    float v = acc[i][j][q] + bv;
                    if (RELU) v = fmaxf(v, 0.f);
                    Cp[(size_t)m * DIM + cnb + j * 16] = f2b(v);
                }
            }
        }
    }
}

// ================= TransE score =================
__global__ __launch_bounds__(256) void k_score(
    const float* __restrict__ V, const float* __restrict__ R,
    const int* __restrict__ triples, const float* __restrict__ gamma,
    float* __restrict__ out, int B)
{
    int t    = (blockIdx.x * 256 + threadIdx.x) >> 6;
    int lane = threadIdx.x & 63;
    if (t >= B) return;
    int h  = triples[t * 3 + 0];
    int r  = triples[t * 3 + 1];
    int tl = triples[t * 3 + 2];
    float4 vh = *(const float4*)(V + (size_t)h  * DIM + lane * 4);
    float4 vr = *(const float4*)(R + (size_t)r  * DIM + lane * 4);
    float4 vt = *(const float4*)(V + (size_t)tl * DIM + lane * 4);
    float dx = vh.x + vr.x - vt.x;
    float dy = vh.y + vr.y - vt.y;
    float dz = vh.z + vr.z - vt.z;
    float dw = vh.w + vr.w - vt.w;
    float s = dx * dx + dy * dy + dz * dz + dw * dw;
    #pragma unroll
    for (int off = 32; off > 0; off >>= 1) s += __shfl_xor(s, off);
    if (lane == 0) out[t] = gamma[0] - sqrtf(s);
}

extern "C" void kernel_launch(void* const* d_in, const int* in_sizes, int n_in,
                              void* d_out, int out_size, void* d_ws, size_t ws_size,
                              hipStream_t stream)
{
    const float* E      = (const float*)d_in[0];
    const float* R      = (const float*)d_in[1];
    const float* lin2_w = (const float*)d_in[2];
    const float* lin2_b = (const float*)d_in[3];
    const float* lin3_w = (const float*)d_in[4];
    const float* lin3_b = (const float*)d_in[5];
    const float* t2e_w  = (const float*)d_in[6];
    const float* t2e_b  = (const float*)d_in[7];
    const float* alpha  = (const float*)d_in[8];
    const float* gamma  = (const float*)d_in[9];
    const int*   et     = (const int*)d_in[10];
    const int*   tt     = (const int*)d_in[11];
    const int*   etet   = (const int*)d_in[12];
    const int*   trip   = (const int*)d_in[13];

    const int NE   = in_sizes[0] / DIM;          // 100000
    const int ET   = in_sizes[10] / 2;           // 900000
    const int TT   = in_sizes[11] / 2;           // 600000
    const int ETET = in_sizes[12] / 2;           // 600000
    const int B    = in_sizes[13] / 3;           // 8192
    const int NTOT = NT + NTET + NE;             // 550000
    const int ETOT = ET + TT + ETET;             // 2.1M

    // ---- workspace layout (~272 MB) ----
    char* ws = (char*)d_ws;
    const size_t P1  = (size_t)NE * DIM * 4;                 // 102.4 MB region end
    const size_t IDX = P1 + (size_t)NT * DIM * 2;            // + 153.6 MB
    unsigned short* EW      = (unsigned short*)ws;           // P0, then:
    unsigned short* tetAgg  = (unsigned short*)ws;
    float*          V       = (float*)ws;
    unsigned short* triEmb  = (unsigned short*)(ws + P1);
    unsigned short* tetEmb  = (unsigned short*)(ws + P1);
    unsigned short* tetProj = (unsigned short*)(ws + P1) + (size_t)NTET * DIM;
    size_t off = IDX;
    int* sortedAll = (int*)(ws + off); off += (size_t)ETOT * 4;
    int* rowOffAll = (int*)(ws + off); off += ((size_t)(NTOT + 1) * 4 + 15) & ~15ull;
    int* cursorAll = (int*)(ws + off); off += (size_t)NTOT * 4;
    int* blockSums = (int*)(ws + off); off += 1040;
    unsigned short* Wb = (unsigned short*)(ws + off); off += 3 * 131072;
    char* zbase = ws + off;                       // contiguous zero region:
    int*      cntAll = (int*)(ws + off);      off += (size_t)NTOT * 4;
    unsigned* bmEnt  = (unsigned*)(ws + off); off += ((size_t)(NE   + 31) / 32) * 4;
    unsigned* bmTet  = (unsigned*)(ws + off); off += ((size_t)(NTET + 31) / 32) * 4;
    unsigned* bmTri  = (unsigned*)(ws + off); off += ((size_t)(NT   + 31) / 32) * 4;
    size_t zsize = (size_t)(ws + off - zbase);
    if (ws_size < off) return;

    unsigned short* W2b = Wb;
    unsigned short* W3b = Wb + 65536;
    unsigned short* Wtb = Wb + 131072;

    // ---- upfront: zero index region, cast weights, big GEMM on E ----
    hipMemsetAsync(zbase, 0, zsize, stream);
    k_cast3<<<192, 256, 0, stream>>>(lin2_w, lin3_w, t2e_w, Wb);
    dim3 gE((NE + 127) / 128, 2);
    k_gemm_mfma<true, false, false><<<gE, 256, 0, stream>>>(E, W2b, nullptr, EW, NE);

    // ---- bitmaps: needEnt <- triples; needTet <- etet|needEnt; needTri <- tt|needTet ----
    k_mark<<<(2 * B + 255) / 256, 256, 0, stream>>>(trip, bmEnt, B);
    k_markf<<<(ETET + 255) / 256, 256, 0, stream>>>(etet + ETET, etet, bmEnt, bmTet, ETET);
    k_markf<<<(TT + 255) / 256, 256, 0, stream>>>(tt, tt + TT, bmTet, bmTri, TT);

    // ---- concatenated count / scan / place over all 3 edge lists ----
    k_count_all<<<(ETOT + 255) / 256, 256, 0, stream>>>(
        et, tt, etet, bmTri, bmTet, bmEnt, cntAll, ET, TT, ETET);
    int nb = (NTOT + SBS * SIT - 1) / (SBS * SIT);
    k_scan_block<<<nb, SBS, 0, stream>>>(cntAll, rowOffAll, blockSums, NTOT);
    k_scan_sums<<<1, SBS, 0, stream>>>(blockSums, nb);
    k_scan_add<<<(NTOT + 255) / 256, 256, 0, stream>>>(rowOffAll, cursorAll,
                                                       blockSums, NTOT, nb);
    k_place_all<<<(ETOT + 255) / 256, 256, 0, stream>>>(
        et, tt, etet, bmTri, bmTet, bmEnt, cursorAll, sortedAll, ET, TT, ETET);

    // ---- stage A: triEmb = relu(mean_et(EW) + b2)  [needTri only] ----
    k_gather<0><<<(NT + 3) / 4, 256, 0, stream>>>(EW, sortedAll, rowOffAll, lin2_b,
                                                  nullptr, nullptr, bmTri, triEmb, NT);

    // ---- stage B: tetAgg = mean_tt(triEmb) [needTet]; tetEmb; tetProj ----
    k_gather<1><<<(NTET + 3) / 4, 256, 0, stream>>>(triEmb, sortedAll, rowOffAll + NT,
                                                    nullptr, nullptr, nullptr, bmTet,
                                                    tetAgg, NTET);
    dim3 gT((NTET + 127) / 128, 2);
    k_gemm_mfma<false, true, true><<<gT, 256, 0, stream>>>(tetAgg, W3b, lin3_b, tetEmb, NTET);
    k_gemm_mfma<false, false, true><<<gT, 256, 0, stream>>>(tetEmb, Wtb, t2e_b, tetProj, NTET);

    // ---- stage C: V = w0*E + w1*mean_etet(tetProj)  [needEnt only] ----
    k_gather<2><<<(NE + 3) / 4, 256, 0, stream>>>(tetProj, sortedAll,
                                                  rowOffAll + NT + NTET, nullptr,
                                                  E, alpha, bmEnt, V, NE);

    // ---- stage D: TransE scores ----
    k_score<<<(B + 3) / 4, 256, 0, stream>>>(V, R, trip, gamma, (float*)d_out, B);
}

// Round 7
// 410.367 us; speedup vs baseline: 20.0644x; 1.1678x over previous
//
#include <hip/hip_runtime.h>
#include <hip/hip_bf16.h>
#include <math.h>

#define DIM 256
#define SBS 256
#define SIT 16           // scan items per thread -> 4096 per block
#define NT   300000
#define NTET 150000

typedef __attribute__((ext_vector_type(8))) short          bf16x8;
typedef __attribute__((ext_vector_type(8))) unsigned short u16x8;
typedef __attribute__((ext_vector_type(4))) float          f32x4;

__device__ inline float b2f(unsigned short u) {
    union { unsigned int i; float f; } c; c.i = ((unsigned int)u) << 16; return c.f;
}
__device__ inline unsigned short f2b(float f) {
    __hip_bfloat16 h = __float2bfloat16(f);
    return *reinterpret_cast<unsigned short*>(&h);
}
__device__ inline bool bmget(const unsigned* bm, int i) {
    return (bm[i >> 5] >> (i & 31)) & 1u;
}

// ================= fused weight cast: 3x [256,256] fp32 -> bf16 =================
__global__ __launch_bounds__(256) void k_cast3(
    const float* __restrict__ w2, const float* __restrict__ w3,
    const float* __restrict__ wt, unsigned short* __restrict__ out)
{
    int i = (blockIdx.x * 256 + threadIdx.x) * 4;      // < 196608
    const float* src; int l;
    if (i < 65536)       { src = w2; l = i; }
    else if (i < 131072) { src = w3; l = i - 65536; }
    else                 { src = wt; l = i - 131072; }
    float4 v = *(const float4*)(src + l);
    ushort4 o; o.x = f2b(v.x); o.y = f2b(v.y); o.z = f2b(v.z); o.w = f2b(v.w);
    *(ushort4*)(out + i) = o;
}

// ================= bitmap marking =================
__global__ __launch_bounds__(256) void k_mark(
    const int* __restrict__ trip, unsigned* __restrict__ bm, int B)
{
    int i = blockIdx.x * 256 + threadIdx.x;
    if (i < 2 * B) {
        int ent = trip[(i >> 1) * 3 + ((i & 1) ? 2 : 0)];
        atomicOr(&bm[ent >> 5], 1u << (ent & 31));
    }
}

// mark bmOut[mi[e]] where bmIn[ci[e]] (test-then-set to cut atomic contention)
__global__ __launch_bounds__(256) void k_markf(
    const int* __restrict__ mi, const int* __restrict__ ci,
    const unsigned* __restrict__ bmIn, unsigned* __restrict__ bmOut, int n)
{
    int e = blockIdx.x * 256 + threadIdx.x;
    if (e < n && bmget(bmIn, ci[e])) {
        int m = mi[e];
        unsigned msk = 1u << (m & 31);
        if (!(bmOut[m >> 5] & msk)) atomicOr(&bmOut[m >> 5], msk);
    }
}

// write needTet bits as scan segment 4
__global__ __launch_bounds__(256) void k_bits(
    const unsigned* __restrict__ bm, int* __restrict__ out, int n)
{
    int i = blockIdx.x * 256 + threadIdx.x;
    if (i < n) out[i] = (bm[i >> 5] >> (i & 31)) & 1u;
}

// ================= concatenated count / scan / place =================
__global__ __launch_bounds__(256) void k_count_all(
    const int* __restrict__ et, const int* __restrict__ tt, const int* __restrict__ etet,
    const unsigned* __restrict__ bmTri, const unsigned* __restrict__ bmTet,
    const unsigned* __restrict__ bmEnt, int* __restrict__ cnt,
    int ET, int TT, int ETET)
{
    int e = blockIdx.x * 256 + threadIdx.x;
    if (e < ET) {
        int d = et[ET + e];
        if (bmget(bmTri, d)) atomicAdd(&cnt[d], 1);
    } else if (e < ET + TT) {
        int i = e - ET;
        int d = tt[TT + i];
        if (bmget(bmTet, d)) atomicAdd(&cnt[NT + d], 1);
    } else if (e < ET + TT + ETET) {
        int i = e - ET - TT;
        int d = etet[i];
        if (bmget(bmEnt, d)) atomicAdd(&cnt[NT + NTET + d], 1);
    }
}

__global__ __launch_bounds__(SBS) void k_scan_block(
    const int* __restrict__ cnt, int* __restrict__ rowOff,
    int* __restrict__ blockSums, int n)
{
    __shared__ int lds[SBS];
    const int t = threadIdx.x;
    const int tbase = blockIdx.x * SBS * SIT + t * SIT;
    int v[SIT]; int tsum = 0;
    #pragma unroll
    for (int i = 0; i < SIT; ++i) {
        int idx = tbase + i;
        v[i] = (idx < n) ? cnt[idx] : 0;
        tsum += v[i];
    }
    lds[t] = tsum;
    __syncthreads();
    #pragma unroll
    for (int off = 1; off < SBS; off <<= 1) {
        int y = (t >= off) ? lds[t - off] : 0;
        __syncthreads();
        lds[t] += y;
        __syncthreads();
    }
    int incl = lds[t];
    int run = incl - tsum;
    #pragma unroll
    for (int i = 0; i < SIT; ++i) {
        int idx = tbase + i;
        if (idx < n) rowOff[idx] = run;
        run += v[i];
    }
    if (t == SBS - 1) blockSums[blockIdx.x] = incl;
}

__global__ __launch_bounds__(SBS) void k_scan_sums(int* __restrict__ bs, int nb)
{
    __shared__ int lds[SBS];
    const int t = threadIdx.x;
    int v = (t < nb) ? bs[t] : 0;
    lds[t] = v;
    __syncthreads();
    #pragma unroll
    for (int off = 1; off < SBS; off <<= 1) {
        int y = (t >= off) ? lds[t - off] : 0;
        __syncthreads();
        lds[t] += y;
        __syncthreads();
    }
    if (t < nb) {
        bs[t] = lds[t] - v;
        if (t == nb - 1) bs[nb] = lds[t];
    }
}

__global__ __launch_bounds__(256) void k_scan_add(
    int* __restrict__ rowOff, int* __restrict__ cursor,
    const int* __restrict__ bs, int n, int nb, int ncur)
{
    int i = blockIdx.x * 256 + threadIdx.x;
    if (i < n) {
        int v = rowOff[i] + bs[i / (SBS * SIT)];
        rowOff[i] = v;
        if (i < ncur) cursor[i] = v;
    }
    if (i == 0) rowOff[n] = bs[nb];
}

__global__ __launch_bounds__(256) void k_place_all(
    const int* __restrict__ et, const int* __restrict__ tt, const int* __restrict__ etet,
    const unsigned* __restrict__ bmTri, const unsigned* __restrict__ bmTet,
    const unsigned* __restrict__ bmEnt, int* __restrict__ cursor,
    int* __restrict__ sorted, int ET, int TT, int ETET)
{
    int e = blockIdx.x * 256 + threadIdx.x;
    if (e < ET) {
        int d = et[ET + e];
        if (bmget(bmTri, d)) sorted[atomicAdd(&cursor[d], 1)] = et[e];
    } else if (e < ET + TT) {
        int i = e - ET;
        int d = tt[TT + i];
        if (bmget(bmTet, d)) sorted[atomicAdd(&cursor[NT + d], 1)] = tt[i];
    } else if (e < ET + TT + ETET) {
        int i = e - ET - TT;
        int d = etet[i];
        if (bmget(bmEnt, d)) sorted[atomicAdd(&cursor[NT + NTET + d], 1)] = etet[ETET + i];
    }
}

// ================= gather-aggregate: half-wave (32 lanes x 16B) per dst row =================
// Wave g handles rows 2g (lanes 0-31) and 2g+1 (lanes 32-63); each load instr
// fetches 1KB = both rows' 512B. 4-deep gated batches for latency hiding.
// EPI 0: out bf16 = relu(mean + bias)          (stage A; skip if !bmTri)
// EPI 1: out bf16 = mean -> compact row cmp[d] (stage B; skip if !bmTet)
// EPI 2: out fp32 = w0*E + w1*mean, src compact (stage C; skip if !bmEnt)
template<int EPI>
__global__ __launch_bounds__(256) void k_gather(
    const unsigned short* __restrict__ src, const int* __restrict__ sorted,
    const int* __restrict__ rowOff, const float* __restrict__ bias,
    const float* __restrict__ E, const float* __restrict__ alpha,
    const unsigned* __restrict__ bm, const int* __restrict__ cmpOff,
    void* __restrict__ out, int ndst)
{
    const int g    = (blockIdx.x * 256 + threadIdx.x) >> 6;
    const int lane = threadIdx.x & 63;
    const int half = lane >> 5;
    const int hl   = lane & 31;
    const int d    = g * 2 + half;
    const bool need = (d < ndst) && bmget(bm, d);
    if (!__any(need)) return;
    const int cmpBase = (EPI >= 1) ? cmpOff[0] : 0;
    int e0 = 0, e1 = 0;
    if (need) { e0 = rowOff[d]; e1 = rowOff[d + 1]; }
    float acc[8] = {0.f, 0.f, 0.f, 0.f, 0.f, 0.f, 0.f, 0.f};
    for (int p = e0; p < e1; p += 4) {
        u16x8 u[4]; float gt[4];
        #pragma unroll
        for (int j = 0; j < 4; ++j) {
            int ee = p + j;
            int ec = (ee < e1) ? ee : (e1 - 1);
            int s  = sorted[ec];
            if (EPI == 2) s = cmpOff[s] - cmpBase;
            u[j]  = *(const u16x8*)(src + (size_t)s * DIM + hl * 8);
            gt[j] = (ee < e1) ? 1.0f : 0.0f;
        }
        #pragma unroll
        for (int j = 0; j < 4; ++j)
            #pragma unroll
            for (int k = 0; k < 8; ++k)
                acc[k] += gt[j] * b2f(u[j][k]);
    }
    float inv = 1.0f / fmaxf((float)(e1 - e0), 1.0f);
    #pragma unroll
    for (int k = 0; k < 8; ++k) acc[k] *= inv;
    if (EPI == 0) {
        float4 bl = *(const float4*)(bias + hl * 8);
        float4 bh = *(const float4*)(bias + hl * 8 + 4);
        float bb[8] = {bl.x, bl.y, bl.z, bl.w, bh.x, bh.y, bh.z, bh.w};
        if (need) {
            u16x8 o;
            #pragma unroll
            for (int k = 0; k < 8; ++k) o[k] = f2b(fmaxf(acc[k] + bb[k], 0.f));
            *(u16x8*)((unsigned short*)out + (size_t)d * DIM + hl * 8) = o;
        }
    } else if (EPI == 1) {
        if (need) {
            int cd = cmpOff[d] - cmpBase;
            u16x8 o;
            #pragma unroll
            for (int k = 0; k < 8; ++k) o[k] = f2b(acc[k]);
            *(u16x8*)((unsigned short*)out + (size_t)cd * DIM + hl * 8) = o;
        }
    } else {
        float a0 = alpha[0], a1v = alpha[1];
        float mx = fmaxf(a0, a1v);
        float x0 = expf(a0 - mx), x1 = expf(a1v - mx);
        float w0 = x0 / (x0 + x1), w1 = x1 / (x0 + x1);
        if (need) {
            const float* er = E + (size_t)d * DIM + hl * 8;
            float4 el = *(const float4*)er;
            float4 eh = *(const float4*)(er + 4);
            float4 o0, o1;
            o0.x = w0 * el.x + w1 * acc[0]; o0.y = w0 * el.y + w1 * acc[1];
            o0.z = w0 * el.z + w1 * acc[2]; o0.w = w0 * el.w + w1 * acc[3];
            o1.x = w0 * eh.x + w1 * acc[4]; o1.y = w0 * eh.y + w1 * acc[5];
            o1.z = w0 * eh.z + w1 * acc[6]; o1.w = w0 * eh.w + w1 * acc[7];
            float* orow = (float*)out + (size_t)d * DIM + hl * 8;
            *(float4*)orow = o0;
            *(float4*)(orow + 4) = o1;
        }
    }
}

// ================= bf16 MFMA GEMM: C = act(A @ W^T [+ b]) =================
// Tile 128x128, BK=64, 256 threads = 4 waves (2x2 of 64x64).
// LDS XOR-swizzle: byte ^= ((row&7)<<4) on both write and read (involution).
// DYNM: M read from device (compact tet count); excess blocks early-exit.
template<bool AF32, bool RELU, bool BIAS, bool DYNM>
__global__ __launch_bounds__(256) void k_gemm_mfma(
    const void* __restrict__ Ap, const unsigned short* __restrict__ Wb,
    const float* __restrict__ bias, unsigned short* __restrict__ Cp,
    int Ms, const int* __restrict__ cmpOff)
{
    int M = Ms;
    if (DYNM) M = cmpOff[NTET] - cmpOff[0];
    const int m0 = blockIdx.x * 128;
    if (m0 >= M) return;
    __shared__ unsigned short As[128 * 64];
    __shared__ unsigned short Ws[128 * 64];
    const int tid  = threadIdx.x;
    const int n0   = blockIdx.y * 128;
    const int wid  = tid >> 6, lane = tid & 63;
    const int wr   = wid >> 1, wc = wid & 1;
    const int sp   = tid & 7;
    const int sr   = tid >> 3;
    const int fr   = lane & 15;
    const int fc   = lane >> 4;

    f32x4 acc[4][4] = {};
    for (int k0 = 0; k0 < DIM; k0 += 64) {
        __syncthreads();
        #pragma unroll
        for (int rr = 0; rr < 4; ++rr) {
            int row = sr + rr * 32;
            int gm  = m0 + row; if (gm >= M) gm = M - 1;
            unsigned off = row * 128 + ((sp * 16) ^ ((row & 7) << 4));
            if (AF32) {
                const float* g = (const float*)Ap + (size_t)gm * DIM + k0 + sp * 8;
                float4 lo = *(const float4*)g;
                float4 hi = *(const float4*)(g + 4);
                u16x8 v;
                v[0] = f2b(lo.x); v[1] = f2b(lo.y); v[2] = f2b(lo.z); v[3] = f2b(lo.w);
                v[4] = f2b(hi.x); v[5] = f2b(hi.y); v[6] = f2b(hi.z); v[7] = f2b(hi.w);
                *(u16x8*)((char*)As + off) = v;
            } else {
                const unsigned short* g = (const unsigned short*)Ap + (size_t)gm * DIM + k0 + sp * 8;
                *(u16x8*)((char*)As + off) = *(const u16x8*)g;
            }
            const unsigned short* gw = Wb + (size_t)(n0 + row) * DIM + k0 + sp * 8;
            *(u16x8*)((char*)Ws + off) = *(const u16x8*)gw;
        }
        __syncthreads();
        #pragma unroll
        for (int kk = 0; kk < 2; ++kk) {
            bf16x8 aF[4], bF[4];
            unsigned cb = kk * 64 + fc * 16;
            #pragma unroll
            for (int i = 0; i < 4; ++i) {
                int arow = wr * 64 + i * 16 + fr;
                aF[i] = *(const bf16x8*)((char*)As + arow * 128 + (cb ^ ((arow & 7) << 4)));
                int wrow = wc * 64 + i * 16 + fr;
                bF[i] = *(const bf16x8*)((char*)Ws + wrow * 128 + (cb ^ ((wrow & 7) << 4)));
            }
            #pragma unroll
            for (int i = 0; i < 4; ++i)
                #pragma unroll
                for (int j = 0; j < 4; ++j)
                    acc[i][j] = __builtin_amdgcn_mfma_f32_16x16x32_bf16(
                        aF[i], bF[j], acc[i][j], 0, 0, 0);
        }
    }
    const int cnb   = n0 + wc * 64 + fr;
    const int rbase = m0 + wr * 64 + fc * 4;
    #pragma unroll
    for (int j = 0; j < 4; ++j) {
        float bv = BIAS ? bias[cnb + j * 16] : 0.0f;
        #pragma unroll
        for (int i = 0; i < 4; ++i) {
            #pragma unroll
            for (int q = 0; q < 4; ++q) {
                int m = rbase + i * 16 + q;
                if (m < M) {
                    float v = acc[i][j][q] + bv;
                    if (RELU) v = fmaxf(v, 0.f);
                    Cp[(size_t)m * DIM + cnb + j * 16] = f2b(v);
                }
            }
        }
    }
}

// ================= TransE score =================
__global__ __launch_bounds__(256) void k_score(
    const float* __restrict__ V, const float* __restrict__ R,
    const int* __restrict__ triples, const float* __restrict__ gamma,
    float* __restrict__ out, int B)
{
    int t    = (blockIdx.x * 256 + threadIdx.x) >> 6;
    int lane = threadIdx.x & 63;
    if (t >= B) return;
    int h  = triples[t * 3 + 0];
    int r  = triples[t * 3 + 1];
    int tl = triples[t * 3 + 2];
    float4 vh = *(const float4*)(V + (size_t)h  * DIM + lane * 4);
    float4 vr = *(const float4*)(R + (size_t)r  * DIM + lane * 4);
    float4 vt = *(const float4*)(V + (size_t)tl * DIM + lane * 4);
    float dx = vh.x + vr.x - vt.x;
    float dy = vh.y + vr.y - vt.y;
    float dz = vh.z + vr.z - vt.z;
    float dw = vh.w + vr.w - vt.w;
    float s = dx * dx + dy * dy + dz * dz + dw * dw;
    #pragma unroll
    for (int off = 32; off > 0; off >>= 1) s += __shfl_xor(s, off);
    if (lane == 0) out[t] = gamma[0] - sqrtf(s);
}

extern "C" void kernel_launch(void* const* d_in, const int* in_sizes, int n_in,
                              void* d_out, int out_size, void* d_ws, size_t ws_size,
                              hipStream_t stream)
{
    const float* E      = (const float*)d_in[0];
    const float* R      = (const float*)d_in[1];
    const float* lin2_w = (const float*)d_in[2];
    const float* lin2_b = (const float*)d_in[3];
    const float* lin3_w = (const float*)d_in[4];
    const float* lin3_b = (const float*)d_in[5];
    const float* t2e_w  = (const float*)d_in[6];
    const float* t2e_b  = (const float*)d_in[7];
    const float* alpha  = (const float*)d_in[8];
    const float* gamma  = (const float*)d_in[9];
    const int*   et     = (const int*)d_in[10];
    const int*   tt     = (const int*)d_in[11];
    const int*   etet   = (const int*)d_in[12];
    const int*   trip   = (const int*)d_in[13];

    const int NE    = in_sizes[0] / DIM;          // 100000
    const int ET    = in_sizes[10] / 2;           // 900000
    const int TT    = in_sizes[11] / 2;           // 600000
    const int ETET  = in_sizes[12] / 2;           // 600000
    const int B     = in_sizes[13] / 3;           // 8192
    const int NTOT  = NT + NTET + NE;             // 550000
    const int NTOT2 = NTOT + NTET;                // 700000 (+ tet bits segment)
    const int ETOT  = ET + TT + ETET;             // 2.1M

    // ---- workspace layout (~272 MB) ----
    char* ws = (char*)d_ws;
    const size_t P1  = (size_t)NE * DIM * 4;
    const size_t IDX = P1 + (size_t)NT * DIM * 2;
    unsigned short* EW      = (unsigned short*)ws;
    unsigned short* tetAgg  = (unsigned short*)ws;
    float*          V       = (float*)ws;
    unsigned short* triEmb  = (unsigned short*)(ws + P1);
    unsigned short* tetEmb  = (unsigned short*)(ws + P1);
    unsigned short* tetProj = (unsigned short*)(ws + P1) + (size_t)NTET * DIM;
    size_t off = IDX;
    int* sortedAll = (int*)(ws + off); off += (size_t)ETOT * 4;
    int* rowOffAll = (int*)(ws + off); off += ((size_t)(NTOT2 + 1) * 4 + 15) & ~15ull;
    int* cursorAll = (int*)(ws + off); off += (size_t)NTOT * 4;
    int* blockSums = (int*)(ws + off); off += 1040;
    unsigned short* Wb = (unsigned short*)(ws + off); off += 3 * 131072;
    char* zbase = ws + off;
    int*      cntAll = (int*)(ws + off);      off += (size_t)NTOT2 * 4;
    unsigned* bmEnt  = (unsigned*)(ws + off); off += ((size_t)(NE   + 31) / 32) * 4;
    unsigned* bmTet  = (unsigned*)(ws + off); off += ((size_t)(NTET + 31) / 32) * 4;
    unsigned* bmTri  = (unsigned*)(ws + off); off += ((size_t)(NT   + 31) / 32) * 4;
    size_t zsize = (size_t)(ws + off - zbase);
    if (ws_size < off) return;

    unsigned short* W2b = Wb;
    unsigned short* W3b = Wb + 65536;
    unsigned short* Wtb = Wb + 131072;
    int* cmpOff = rowOffAll + NTOT;               // tet -> compact row map (prefix)

    // ---- upfront: zero index region, cast weights, big GEMM on E ----
    hipMemsetAsync(zbase, 0, zsize, stream);
    k_cast3<<<192, 256, 0, stream>>>(lin2_w, lin3_w, t2e_w, Wb);
    dim3 gE((NE + 127) / 128, 2);
    k_gemm_mfma<true, false, false, false><<<gE, 256, 0, stream>>>(
        E, W2b, nullptr, EW, NE, nullptr);

    // ---- bitmaps: needEnt <- triples; needTet <- etet|needEnt; needTri <- tt|needTet ----
    k_mark<<<(2 * B + 255) / 256, 256, 0, stream>>>(trip, bmEnt, B);
    k_markf<<<(ETET + 255) / 256, 256, 0, stream>>>(etet + ETET, etet, bmEnt, bmTet, ETET);
    k_markf<<<(TT + 255) / 256, 256, 0, stream>>>(tt, tt + TT, bmTet, bmTri, TT);
    k_bits<<<(NTET + 255) / 256, 256, 0, stream>>>(bmTet, cntAll + NTOT, NTET);

    // ---- concatenated count / scan / place (edges + tet-bits segment) ----
    k_count_all<<<(ETOT + 255) / 256, 256, 0, stream>>>(
        et, tt, etet, bmTri, bmTet, bmEnt, cntAll, ET, TT, ETET);
    int nb = (NTOT2 + SBS * SIT - 1) / (SBS * SIT);
    k_scan_block<<<nb, SBS, 0, stream>>>(cntAll, rowOffAll, blockSums, NTOT2);
    k_scan_sums<<<1, SBS, 0, stream>>>(blockSums, nb);
    k_scan_add<<<(NTOT2 + 255) / 256, 256, 0, stream>>>(rowOffAll, cursorAll,
                                                        blockSums, NTOT2, nb, NTOT);
    k_place_all<<<(ETOT + 255) / 256, 256, 0, stream>>>(
        et, tt, etet, bmTri, bmTet, bmEnt, cursorAll, sortedAll, ET, TT, ETET);

    // ---- stage A: triEmb = relu(mean_et(EW) + b2)  [needTri only] ----
    k_gather<0><<<(NT + 7) / 8, 256, 0, stream>>>(EW, sortedAll, rowOffAll, lin2_b,
                                                  nullptr, nullptr, bmTri, cmpOff,
                                                  triEmb, NT);

    // ---- stage B: tetAgg = mean_tt(triEmb) compact; tetEmb; tetProj ----
    k_gather<1><<<(NTET + 7) / 8, 256, 0, stream>>>(triEmb, sortedAll, rowOffAll + NT,
                                                    nullptr, nullptr, nullptr, bmTet,
                                                    cmpOff, tetAgg, NTET);
    dim3 gT((NTET + 127) / 128, 2);
    k_gemm_mfma<false, true, true, true><<<gT, 256, 0, stream>>>(
        tetAgg, W3b, lin3_b, tetEmb, NTET, cmpOff);
    k_gemm_mfma<false, false, true, true><<<gT, 256, 0, stream>>>(
        tetEmb, Wtb, t2e_b, tetProj, NTET, cmpOff);

    // ---- stage C: V = w0*E + w1*mean_etet(tetProj[cmp])  [needEnt only] ----
    k_gather<2><<<(NE + 7) / 8, 256, 0, stream>>>(tetProj, sortedAll,
                                                  rowOffAll + NT + NTET, nullptr,
                                                  E, alpha, bmEnt, cmpOff, V, NE);

    // ---- stage D: TransE scores ----
    k_score<<<(B + 3) / 4, 256, 0, stream>>>(V, R, trip, gamma, (float*)d_out, B);
}